// Round 12
// baseline (764.869 us; speedup 1.0000x reference)
//
#include <hip/hip_runtime.h>
#include <hip/hip_cooperative_groups.h>
#include <math.h>

namespace cg = cooperative_groups;

#define T_SEQ 2048

typedef float  fx4 __attribute__((ext_vector_type(4)));
typedef short  sx4 __attribute__((ext_vector_type(4)));
typedef short  sx8 __attribute__((ext_vector_type(8)));
typedef unsigned short u16;

static __device__ __forceinline__ u16 f2b(float f) {
  unsigned u = __builtin_bit_cast(unsigned, f);
  u += 0x7fffu + ((u >> 16) & 1u);   // RNE
  return (u16)(u >> 16);
}
static __device__ __forceinline__ float b2f(u16 v) {
  unsigned u = ((unsigned)v) << 16;
  return __builtin_bit_cast(float, u);
}

static __device__ __forceinline__ fx4 mfma16(sx4 a, sx4 b, fx4 c) {
  return __builtin_amdgcn_mfma_f32_16x16x16bf16_1k(a, b, c, 0, 0, 0);
}
static __device__ __forceinline__ fx4 mfma32(sx8 a, sx8 b, fx4 c) {
  return __builtin_amdgcn_mfma_f32_16x16x32_bf16(a, b, c, 0, 0, 0);
}

static __device__ __forceinline__ void gload16(const void* g, void* l) {
  __builtin_amdgcn_global_load_lds(
      (const __attribute__((address_space(1))) unsigned*)g,
      (__attribute__((address_space(3))) unsigned*)l, 16, 0, 0);
}

// =================== stage bodies (shared by mega + fallback) ===============

// ---- GEMM: 512 threads (2x4 waves), BK=64 dbuf, XOR-swizzled LDS,
//      XCD-grouped decode, coalesced epilogue via LDS C-tile.
template <int BM, int BN, int KD, int ND, int OP, int NGRP>
static __device__ __forceinline__ void gemm_body(char* smem, int id,
                                                 const u16* __restrict__ A,
                                                 const u16* __restrict__ Wt,
                                                 const float* __restrict__ bias,
                                                 const float* __restrict__ resid,
                                                 void* __restrict__ outp) {
  constexpr int BK = 64;
  constexpr int NTH = 512;
  constexpr int WTM = BM / 2, WTN = BN / 4;
  constexpr int FM = WTM / 16, FN = WTN / 16;
  constexpr int NT = KD / BK;
  auto As = (u16(*)[BM][BK])smem;
  auto Bs = (u16(*)[BN][BK])(smem + 2 * BM * BK * 2);
  const int tid = threadIdx.x;
  const int bm = ((id & 7) + 8 * ((id >> 3) / NGRP)) * BM;
  const int bn = ((id >> 3) % NGRP) * BN;
  const int l = tid & 63, wid = tid >> 6;
  const int wr = wid >> 2, wc = wid & 3;
  const int lq = l & 15, lg = l >> 4;

  __syncthreads();  // previous smem use (epilogue / prior stage) done

  auto stage = [&](int buf, int k0) {
#pragma unroll
    for (int i = 0; i < (BM * 8 + NTH - 1) / NTH; ++i) {
      const int p = tid + i * NTH;
      if (BM * 8 % NTH == 0 || p < BM * 8) {
        const int row = p >> 3, ch = p & 7;
        gload16(&A[(size_t)(bm + row) * KD + k0 + ((ch ^ (row & 7)) << 3)],
                &As[buf][row][ch << 3]);
      }
    }
#pragma unroll
    for (int i = 0; i < (BN * 8 + NTH - 1) / NTH; ++i) {
      const int p = tid + i * NTH;
      if (BN * 8 % NTH == 0 || p < BN * 8) {
        const int row = p >> 3, ch = p & 7;
        gload16(&Wt[(size_t)(bn + row) * KD + k0 + ((ch ^ (row & 7)) << 3)],
                &Bs[buf][row][ch << 3]);
      }
    }
  };

  fx4 acc[FM][FN] = {};
  stage(0, 0);
  int cur = 0;
  for (int t = 0; t < NT; ++t) {
    __syncthreads();
    if (t + 1 < NT) stage(cur ^ 1, (t + 1) * BK);
#pragma unroll
    for (int kk = 0; kk < BK; kk += 32) {
      sx8 aF[FM], bF[FN];
#pragma unroll
      for (int m = 0; m < FM; ++m) {
        const int row = wr * WTM + m * 16 + lq;
        aF[m] = *(const sx8*)&As[cur][row][((((kk >> 3) + lg) ^ (row & 7)) << 3)];
      }
#pragma unroll
      for (int n = 0; n < FN; ++n) {
        const int row = wc * WTN + n * 16 + lq;
        bF[n] = *(const sx8*)&Bs[cur][row][((((kk >> 3) + lg) ^ (row & 7)) << 3)];
      }
#pragma unroll
      for (int m = 0; m < FM; ++m)
#pragma unroll
        for (int n = 0; n < FN; ++n) acc[m][n] = mfma32(aF[m], bF[n], acc[m][n]);
    }
    cur ^= 1;
  }

  __syncthreads();  // all LDS reads done; reuse smem as C tile
  if (OP == 1) {
    auto C = (float(*)[BN + 8])smem;
#pragma unroll
    for (int m = 0; m < FM; ++m)
#pragma unroll
      for (int n = 0; n < FN; ++n) {
        const int col = wc * WTN + n * 16 + lq;
        const float bv = bias[bn + col];
#pragma unroll
        for (int r = 0; r < 4; ++r)
          C[wr * WTM + m * 16 + lg * 4 + r][col] = acc[m][n][r] + bv;
      }
    __syncthreads();
    constexpr int CH = (BM * BN / 4) / NTH;
#pragma unroll
    for (int i = 0; i < CH; ++i) {
      const int t = tid + i * NTH;
      const int row = t / (BN / 4), c = t % (BN / 4);
      fx4 v = *(const fx4*)&C[row][c * 4];
      v += *(const fx4*)&resid[(size_t)(bm + row) * ND + bn + c * 4];
      *(fx4*)&((float*)outp)[(size_t)(bm + row) * ND + bn + c * 4] = v;
    }
  } else {
    auto C = (u16(*)[BN + 8])smem;
#pragma unroll
    for (int m = 0; m < FM; ++m)
#pragma unroll
      for (int n = 0; n < FN; ++n) {
        const int col = wc * WTN + n * 16 + lq;
        const float bv = bias[bn + col];
#pragma unroll
        for (int r = 0; r < 4; ++r) {
          float v = acc[m][n][r] + bv;
          if (OP == 2) v = 0.5f * v * (1.0f + erff(v * 0.70710678118654752f));
          C[wr * WTM + m * 16 + lg * 4 + r][col] = f2b(v);
        }
      }
    __syncthreads();
    constexpr int CH = (BM * BN / 8) / NTH;
#pragma unroll
    for (int i = 0; i < CH; ++i) {
      const int t = tid + i * NTH;
      const int row = t / (BN / 8), c = t % (BN / 8);
      *(sx8*)&((u16*)outp)[(size_t)(bm + row) * ND + bn + c * 8] = *(const sx8*)&C[row][c * 8];
    }
  }
}

// ---- banded flash attention body, 128-q tiles, one-pass softmax ----
static __device__ __forceinline__ void attn_body(char* smem, int blk,
                                                 const u16* __restrict__ qkv,
                                                 u16* __restrict__ o) {
  auto Qs = (u16(*)[32])smem;            // [128][32]
  auto Ks = (u16(*)[32])(smem + 8192);   // [256][32]
  auto Vs = (u16(*)[264])(smem + 24576); // [32][264]
  const int tile = blk & 15;
  const int bh = blk >> 4;
  const int h = bh & 7;
  const int b = bh >> 3;
  const int q0 = tile << 7;
  const int kstart = max(0, q0 - 64);
  const int kend = min(T_SEQ, q0 + 192);
  const int nk = kend - kstart;
  const int tid = threadIdx.x;
  const float scale = 0.17677669529663687f;  // 1/sqrt(32)

  __syncthreads();
  {
    const int r = tid >> 2, c8 = (tid & 3) << 3;
    gload16(&qkv[(size_t)(b * T_SEQ + q0 + r) * 768 + h * 32 + c8], &Qs[r][c8]);
  }
  for (int r0 = 0; r0 < nk; r0 += 128) {
    const int r = r0 + (tid >> 2);
    if (r < nk) {
      const int c8 = (tid & 3) << 3;
      gload16(&qkv[(size_t)(b * T_SEQ + kstart + r) * 768 + 256 + h * 32 + c8], &Ks[r][c8]);
    }
  }
  for (int e = tid * 4; e < nk * 32; e += 2048) {
    const int r = e >> 5, c = e & 31;
    sx4 v = *(const sx4*)&qkv[(size_t)(b * T_SEQ + kstart + r) * 768 + 512 + h * 32 + c];
    Vs[c + 0][r] = v[0];
    Vs[c + 1][r] = v[1];
    Vs[c + 2][r] = v[2];
    Vs[c + 3][r] = v[3];
  }
  __syncthreads();

  const int w = tid >> 6, l = tid & 63;
  const int lq = l & 15, lg = l >> 4;
  const int qw0 = q0 + w * 16;
  const int iq = qw0 + lq;
  const sx8 qB = *(const sx8*)&Qs[w * 16 + lq][8 * lg];
  float lsum = 0.0f;
  fx4 acc0 = {0.f, 0.f, 0.f, 0.f}, acc1 = {0.f, 0.f, 0.f, 0.f};
  const int rt0 = max(0, qw0 - 64 - kstart) >> 4;
  const int rt1 = (min(kend, qw0 + 80) - kstart) >> 4;
  for (int rt = rt0; rt < rt1; ++rt) {
    const int kb = kstart + (rt << 4);
    const sx8 kA = *(const sx8*)&Ks[(rt << 4) + lq][8 * lg];
    fx4 zero = {0.f, 0.f, 0.f, 0.f};
    fx4 sc = mfma32(kA, qB, zero);
    sx4 pB;
#pragma unroll
    for (int r = 0; r < 4; ++r) {
      const int dd = kb + 4 * lg + r - iq;
      const float sv = (dd >= -64 && dd <= 64) ? fminf(sc[r] * scale, 30.0f) : -100.0f;
      const float p = __expf(sv);
      lsum += p;
      pB[r] = (short)f2b(p);
    }
    const sx4 vA0 = *(const sx4*)&Vs[lq][(rt << 4) + 4 * lg];
    const sx4 vA1 = *(const sx4*)&Vs[16 + lq][(rt << 4) + 4 * lg];
    acc0 = mfma16(vA0, pB, acc0);
    acc1 = mfma16(vA1, pB, acc1);
  }
  lsum += __shfl_xor(lsum, 16);
  lsum += __shfl_xor(lsum, 32);
  const float rl = 1.0f / lsum;

  __syncthreads();
  auto Os = (u16(*)[32])Qs;
#pragma unroll
  for (int r = 0; r < 4; ++r) {
    Os[w * 16 + lq][4 * lg + r] = f2b(acc0[r] * rl);
    Os[w * 16 + lq][16 + 4 * lg + r] = f2b(acc1[r] * rl);
  }
  __syncthreads();
  {
    const int row = tid >> 2, c = tid & 3;
    *(sx8*)&o[(size_t)(b * T_SEQ + q0 + row) * 256 + h * 32 + c * 8] =
        *(const sx8*)&Os[row][c * 8];
  }
}

// ---- fused out-proj + bias + x-residual(bf16) + LN2 body (16 rows) ----
static __device__ __forceinline__ void gemmln_body(char* smem, int bid,
                                                   const u16* __restrict__ A,
                                                   const u16* __restrict__ Wt,
                                                   const float* __restrict__ bias,
                                                   const u16* __restrict__ xb,
                                                   const float* __restrict__ g,
                                                   const float* __restrict__ bv2,
                                                   u16* __restrict__ yn) {
  auto As = (u16(*)[16][64])smem;              // [2][16][64]
  auto Bs = (u16(*)[256][64])(smem + 4096);    // [2][256][64]
  auto red = (float(*)[8][2])(smem + 69632);   // [16][8][2]
  auto Ys = (u16(*)[264])smem;                 // [16][264] (aliases As/Bs)
  const int tid = threadIdx.x;
  const int bm = bid * 16;
  const int l = tid & 63, wc = tid >> 6;       // 8 waves, all wr=0
  const int lq = l & 15, lg = l >> 4;

  __syncthreads();

  auto stage = [&](int buf, int k0) {
    if (tid < 128) {
      const int row = tid >> 3, ch = tid & 7;
      gload16(&A[(size_t)(bm + row) * 256 + k0 + ((ch ^ (row & 7)) << 3)],
              &As[buf][row][ch << 3]);
    }
#pragma unroll
    for (int i = 0; i < 4; ++i) {
      const int p = tid + i * 512;
      const int row = p >> 3, ch = p & 7;
      gload16(&Wt[(size_t)row * 256 + k0 + ((ch ^ (row & 7)) << 3)],
              &Bs[buf][row][ch << 3]);
    }
  };

  fx4 acc[2] = {};
  stage(0, 0);
  int cur = 0;
  for (int t = 0; t < 4; ++t) {
    __syncthreads();
    if (t + 1 < 4) stage(cur ^ 1, (t + 1) * 64);
#pragma unroll
    for (int kk = 0; kk < 64; kk += 32) {
      const sx8 aF = *(const sx8*)&As[cur][lq][((((kk >> 3) + lg) ^ (lq & 7)) << 3)];
#pragma unroll
      for (int n = 0; n < 2; ++n) {
        const int brow = wc * 32 + n * 16 + lq;
        const sx8 bF = *(const sx8*)&Bs[cur][brow][((((kk >> 3) + lg) ^ (brow & 7)) << 3)];
        acc[n] = mfma32(aF, bF, acc[n]);
      }
    }
    cur ^= 1;
  }

  float vv[2][4];
  float s[4] = {}, q[4] = {};
#pragma unroll
  for (int n = 0; n < 2; ++n) {
    const int col = wc * 32 + n * 16 + lq;
    const float bb = bias[col];
#pragma unroll
    for (int r = 0; r < 4; ++r) {
      const int row = bm + lg * 4 + r;
      const float v = acc[n][r] + bb + b2f(xb[(size_t)row * 256 + col]);
      vv[n][r] = v;
      s[r] += v;
      q[r] += v * v;
    }
  }
#pragma unroll
  for (int off = 1; off < 16; off <<= 1) {
#pragma unroll
    for (int r = 0; r < 4; ++r) {
      s[r] += __shfl_xor(s[r], off);
      q[r] += __shfl_xor(q[r], off);
    }
  }
  __syncthreads();
  if (lq == 0) {
#pragma unroll
    for (int r = 0; r < 4; ++r) {
      red[lg * 4 + r][wc][0] = s[r];
      red[lg * 4 + r][wc][1] = q[r];
    }
  }
  __syncthreads();
  float mean4[4], rs4[4];
#pragma unroll
  for (int r = 0; r < 4; ++r) {
    const int rr = lg * 4 + r;
    float st = 0.f, qt = 0.f;
#pragma unroll
    for (int w8 = 0; w8 < 8; ++w8) {
      st += red[rr][w8][0];
      qt += red[rr][w8][1];
    }
    mean4[r] = st * (1.0f / 256.0f);
    const float var = qt * (1.0f / 256.0f) - mean4[r] * mean4[r];
    rs4[r] = rsqrtf(var + 1e-5f);
  }
  __syncthreads();
#pragma unroll
  for (int n = 0; n < 2; ++n) {
    const int col = wc * 32 + n * 16 + lq;
    const float gc = g[col], bc = bv2[col];
#pragma unroll
    for (int r = 0; r < 4; ++r)
      Ys[lg * 4 + r][col] = f2b((vv[n][r] - mean4[r]) * rs4[r] * gc + bc);
  }
  __syncthreads();
  {
    const int row = tid >> 5, c = tid & 31;
    *(sx8*)&yn[(size_t)(bm + row) * 256 + c * 8] = *(const sx8*)&Ys[row][c * 8];
  }
}

// =========================== megakernel =====================================
struct MegaArgs {
  const float *x, *ln1g, *ln1b, *ipw, *ipb, *outw, *outb, *ln2g, *ln2b, *w1, *b1, *w2, *b2;
  u16 *xn, *xb, *qkvb, *o, *yn, *hh, *ipwT, *outwT, *w1T, *w2T;
  float* out;
};

__global__ __launch_bounds__(512, 4) void mega_k(MegaArgs a) {
  __shared__ __align__(16) char smem[70656];
  cg::grid_group grid = cg::this_grid();
  const int bid = blockIdx.x, tid = threadIdx.x;

  // ---- stage 0: LN1 + x->bf16 (16 rows/block) + weight transposes ----
  {
    const int l = tid & 63, wv = tid >> 6;
#pragma unroll
    for (int p = 0; p < 2; ++p) {
      const int row = bid * 16 + p * 8 + wv;
      fx4 v = *(const fx4*)&a.x[(size_t)row * 256 + l * 4];
      float s = v.x + v.y + v.z + v.w;
      float q = v.x * v.x + v.y * v.y + v.z * v.z + v.w * v.w;
#pragma unroll
      for (int off = 1; off < 64; off <<= 1) {
        s += __shfl_xor(s, off);
        q += __shfl_xor(q, off);
      }
      const float mean = s * (1.0f / 256.0f);
      const float var = q * (1.0f / 256.0f) - mean * mean;
      const float rstd = rsqrtf(var + 1e-5f);
      fx4 gv = *(const fx4*)&a.ln1g[l * 4];
      fx4 bv = *(const fx4*)&a.ln1b[l * 4];
      sx4 o_, xo;
      o_[0] = (short)f2b((v.x - mean) * rstd * gv.x + bv.x);
      o_[1] = (short)f2b((v.y - mean) * rstd * gv.y + bv.y);
      o_[2] = (short)f2b((v.z - mean) * rstd * gv.z + bv.z);
      o_[3] = (short)f2b((v.w - mean) * rstd * gv.w + bv.w);
      xo[0] = (short)f2b(v.x);
      xo[1] = (short)f2b(v.y);
      xo[2] = (short)f2b(v.z);
      xo[3] = (short)f2b(v.w);
      *(sx4*)&a.xn[(size_t)row * 256 + l * 4] = o_;
      *(sx4*)&a.xb[(size_t)row * 256 + l * 4] = xo;
    }
    auto tt = (float(*)[33])smem;
    for (int tb = bid; tb < 768; tb += 512) {
      const float* in; u16* outp; int K, N, loc;
      if (tb < 192)      { in = a.ipw;  outp = a.ipwT;  K = 256;  N = 768;  loc = tb; }
      else if (tb < 256) { in = a.outw; outp = a.outwT; K = 256;  N = 256;  loc = tb - 192; }
      else if (tb < 512) { in = a.w1;   outp = a.w1T;   K = 256;  N = 1024; loc = tb - 256; }
      else               { in = a.w2;   outp = a.w2T;   K = 1024; N = 256;  loc = tb - 512; }
      const int ntx = N >> 5;
      const int by = (loc / ntx) << 5;
      const int bx = (loc % ntx) << 5;
      const int c = tid & 31, r0 = tid >> 5;  // r0 in 0..15
      __syncthreads();
#pragma unroll
      for (int i = 0; i < 2; ++i)
        tt[r0 + i * 16][c] = in[(size_t)(by + r0 + i * 16) * N + bx + c];
      __syncthreads();
#pragma unroll
      for (int i = 0; i < 2; ++i) {
        const int r = r0 + i * 16;
        outp[(size_t)(bx + r) * K + by + c] = f2b(tt[c][r]);
      }
    }
  }
  __threadfence();
  grid.sync();

  // ---- stage 1: qkv projection (768 tiles over 512 blocks) ----
  for (int t1 = bid; t1 < 768; t1 += 512)
    gemm_body<64, 128, 256, 768, 0, 6>(smem, t1, a.xn, a.ipwT, a.ipb, nullptr, a.qkvb);
  __threadfence();
  grid.sync();

  // ---- stage 2: banded attention ----
  attn_body(smem, bid, a.qkvb, a.o);
  __threadfence();
  grid.sync();

  // ---- stage 3: out-proj + residual + LN2 ----
  gemmln_body(smem, bid, a.o, a.outwT, a.outb, a.xb, a.ln2g, a.ln2b, a.yn);
  __threadfence();
  grid.sync();

  // ---- stage 4: ff1 + GELU ----
  gemm_body<128, 128, 256, 1024, 2, 8>(smem, bid, a.yn, a.w1T, a.b1, nullptr, a.hh);
  __threadfence();
  grid.sync();

  // ---- stage 5: ff2 + bias + x residual ----
  gemm_body<32, 128, 1024, 256, 1, 2>(smem, bid, a.hh, a.w2T, a.b2, a.x, a.out);
}

// =================== fallback wrappers (R11 proven path) ====================
__global__ __launch_bounds__(256) void prep_k(
    const float* __restrict__ x, const float* __restrict__ g1,
    const float* __restrict__ b1, u16* __restrict__ xn, u16* __restrict__ xb,
    const float* __restrict__ ipw, const float* __restrict__ outw,
    const float* __restrict__ w1, const float* __restrict__ w2,
    u16* __restrict__ ipwT, u16* __restrict__ outwT,
    u16* __restrict__ w1T, u16* __restrict__ w2T) {
  const int bid = blockIdx.x;
  if (bid < 2048) {
    const int row = bid * 4 + (threadIdx.x >> 6);
    const int l = threadIdx.x & 63;
    fx4 v = *(const fx4*)&x[(size_t)row * 256 + l * 4];
    float s = v.x + v.y + v.z + v.w;
    float q = v.x * v.x + v.y * v.y + v.z * v.z + v.w * v.w;
#pragma unroll
    for (int off = 1; off < 64; off <<= 1) {
      s += __shfl_xor(s, off);
      q += __shfl_xor(q, off);
    }
    const float mean = s * (1.0f / 256.0f);
    const float var = q * (1.0f / 256.0f) - mean * mean;
    const float rstd = rsqrtf(var + 1e-5f);
    fx4 gv = *(const fx4*)&g1[l * 4];
    fx4 bv = *(const fx4*)&b1[l * 4];
    sx4 o, xo;
    o[0] = (short)f2b((v.x - mean) * rstd * gv.x + bv.x);
    o[1] = (short)f2b((v.y - mean) * rstd * gv.y + bv.y);
    o[2] = (short)f2b((v.z - mean) * rstd * gv.z + bv.z);
    o[3] = (short)f2b((v.w - mean) * rstd * gv.w + bv.w);
    xo[0] = (short)f2b(v.x);
    xo[1] = (short)f2b(v.y);
    xo[2] = (short)f2b(v.z);
    xo[3] = (short)f2b(v.w);
    *(sx4*)&xn[(size_t)row * 256 + l * 4] = o;
    *(sx4*)&xb[(size_t)row * 256 + l * 4] = xo;
    return;
  }
  const int tb = bid - 2048;
  const float* in; u16* out; int K, N, loc;
  if (tb < 192)      { in = ipw;  out = ipwT;  K = 256;  N = 768;  loc = tb; }
  else if (tb < 256) { in = outw; out = outwT; K = 256;  N = 256;  loc = tb - 192; }
  else if (tb < 512) { in = w1;   out = w1T;   K = 256;  N = 1024; loc = tb - 256; }
  else               { in = w2;   out = w2T;   K = 1024; N = 256;  loc = tb - 512; }
  const int ntx = N >> 5;
  const int by = (loc / ntx) << 5;
  const int bx = (loc % ntx) << 5;
  __shared__ float t[32][33];
  const int c = threadIdx.x & 31, r0 = threadIdx.x >> 5;
#pragma unroll
  for (int i = 0; i < 4; ++i)
    t[r0 + i * 8][c] = in[(size_t)(by + r0 + i * 8) * N + bx + c];
  __syncthreads();
#pragma unroll
  for (int i = 0; i < 4; ++i) {
    const int r = r0 + i * 8;
    out[(size_t)(bx + r) * K + by + c] = f2b(t[c][r]);
  }
}

template <int BM, int BN, int KD, int ND, int OP, int NGRP>
__global__ __launch_bounds__(512) void gemm6_k(const u16* __restrict__ A,
                                               const u16* __restrict__ Wt,
                                               const float* __restrict__ bias,
                                               const float* __restrict__ resid,
                                               void* __restrict__ outp) {
  __shared__ __align__(16) char smem[(2 * BM + 2 * BN) * 64 * 2];
  gemm_body<BM, BN, KD, ND, OP, NGRP>(smem, blockIdx.x, A, Wt, bias, resid, outp);
}

__global__ __launch_bounds__(512) void gemmln_k(const u16* __restrict__ A,
                                                const u16* __restrict__ Wt,
                                                const float* __restrict__ bias,
                                                const u16* __restrict__ xb,
                                                const float* __restrict__ g,
                                                const float* __restrict__ bv2,
                                                u16* __restrict__ yn) {
  __shared__ __align__(16) char smem[70656];
  gemmln_body(smem, blockIdx.x, A, Wt, bias, xb, g, bv2, yn);
}

__global__ __launch_bounds__(512) void attn_k(const u16* __restrict__ qkv,
                                              u16* __restrict__ o) {
  __shared__ __align__(16) char smem[41472];
  attn_body(smem, blockIdx.x, qkv, o);
}

extern "C" void kernel_launch(void* const* d_in, const int* in_sizes, int n_in,
                              void* d_out, int out_size, void* d_ws, size_t ws_size,
                              hipStream_t stream) {
  const float* x    = (const float*)d_in[0];
  const float* ln1g = (const float*)d_in[1];
  const float* ln1b = (const float*)d_in[2];
  const float* ipw  = (const float*)d_in[3];
  const float* ipb  = (const float*)d_in[4];
  const float* outw = (const float*)d_in[5];
  const float* outb = (const float*)d_in[6];
  const float* ln2g = (const float*)d_in[7];
  const float* ln2b = (const float*)d_in[8];
  const float* w1   = (const float*)d_in[9];
  const float* b1   = (const float*)d_in[10];
  const float* w2   = (const float*)d_in[11];
  const float* b2   = (const float*)d_in[12];

  char* ws = (char*)d_ws;
  u16*   xn   = (u16*)(ws);                          // 4 MB  bf16 [8192][256]
  u16*   qkvb = (u16*)(ws + (4ull << 20));           // 12 MB bf16 [8192][768]
  u16*   o    = (u16*)(ws + (16ull << 20));          // 4 MB  bf16 [8192][256]
  u16*   yn   = (u16*)(ws + (20ull << 20));          // 4 MB  bf16 [8192][256]
  u16*   hh   = (u16*)(ws + (24ull << 20));          // 16 MB bf16 [8192][1024]
  u16*   xb   = (u16*)(ws + (40ull << 20));          // 4 MB  bf16 [8192][256]
  u16*   ipwT = (u16*)(ws + (44ull << 20));          // 384 KB bf16 [768][256]
  u16*   outwT= (u16*)(ws + (44ull << 20) + (512ull << 10));   // 128 KB [256][256]
  u16*   w1T  = (u16*)(ws + (45ull << 20));          // 512 KB bf16 [1024][256]
  u16*   w2T  = (u16*)(ws + (45ull << 20) + (512ull << 10));   // 512 KB [256][1024]

  MegaArgs a;
  a.x = x; a.ln1g = ln1g; a.ln1b = ln1b; a.ipw = ipw; a.ipb = ipb;
  a.outw = outw; a.outb = outb; a.ln2g = ln2g; a.ln2b = ln2b;
  a.w1 = w1; a.b1 = b1; a.w2 = w2; a.b2 = b2;
  a.xn = xn; a.xb = xb; a.qkvb = qkvb; a.o = o; a.yn = yn; a.hh = hh;
  a.ipwT = ipwT; a.outwT = outwT; a.w1T = w1T; a.w2T = w2T;
  a.out = (float*)d_out;

  void* kargs[] = {(void*)&a};
  hipError_t err = hipLaunchCooperativeKernel((void*)mega_k, dim3(512), dim3(512),
                                              kargs, 0, stream);
  if (err != hipSuccess) {
    // fallback: proven 6-kernel path
    prep_k<<<2816, 256, 0, stream>>>(x, ln1g, ln1b, xn, xb, ipw, outw, w1, w2,
                                     ipwT, outwT, w1T, w2T);
    gemm6_k<64, 128, 256, 768, 0, 6><<<768, 512, 0, stream>>>(xn, ipwT, ipb, nullptr, qkvb);
    attn_k<<<512, 512, 0, stream>>>(qkvb, o);
    gemmln_k<<<512, 512, 0, stream>>>(o, outwT, outb, xb, ln2g, ln2b, yn);
    gemm6_k<128, 128, 256, 1024, 2, 8><<<512, 512, 0, stream>>>(yn, w1T, b1, nullptr, hh);
    gemm6_k<32, 128, 1024, 256, 1, 2><<<512, 512, 0, stream>>>(hh, w2T, b2, x, (float*)d_out);
  }
}

// Round 13
// 764.331 us; speedup vs baseline: 1.0007x; 1.0007x over previous
//
#include <hip/hip_runtime.h>
#include <hip/hip_cooperative_groups.h>
#include <math.h>

namespace cg = cooperative_groups;

#define T_SEQ 2048

typedef float  fx4 __attribute__((ext_vector_type(4)));
typedef short  sx4 __attribute__((ext_vector_type(4)));
typedef short  sx8 __attribute__((ext_vector_type(8)));
typedef unsigned short u16;

static __device__ __forceinline__ u16 f2b(float f) {
  unsigned u = __builtin_bit_cast(unsigned, f);
  u += 0x7fffu + ((u >> 16) & 1u);   // RNE
  return (u16)(u >> 16);
}
static __device__ __forceinline__ float b2f(u16 v) {
  unsigned u = ((unsigned)v) << 16;
  return __builtin_bit_cast(float, u);
}

static __device__ __forceinline__ fx4 mfma16(sx4 a, sx4 b, fx4 c) {
  return __builtin_amdgcn_mfma_f32_16x16x16bf16_1k(a, b, c, 0, 0, 0);
}
static __device__ __forceinline__ fx4 mfma32(sx8 a, sx8 b, fx4 c) {
  return __builtin_amdgcn_mfma_f32_16x16x32_bf16(a, b, c, 0, 0, 0);
}

static __device__ __forceinline__ void gload16(const void* g, void* l) {
  __builtin_amdgcn_global_load_lds(
      (const __attribute__((address_space(1))) unsigned*)g,
      (__attribute__((address_space(3))) unsigned*)l, 16, 0, 0);
}

// =================== stage bodies (shared by mega + fallback) ===============

// ---- GEMM: 512 threads (2x4 waves), BK=64 dbuf, XOR-swizzled LDS,
//      XCD-grouped decode, coalesced epilogue via LDS C-tile.
template <int BM, int BN, int KD, int ND, int OP, int NGRP>
static __device__ __forceinline__ void gemm_body(char* smem, int id,
                                                 const u16* __restrict__ A,
                                                 const u16* __restrict__ Wt,
                                                 const float* __restrict__ bias,
                                                 const float* __restrict__ resid,
                                                 void* __restrict__ outp) {
  constexpr int BK = 64;
  constexpr int NTH = 512;
  constexpr int WTM = BM / 2, WTN = BN / 4;
  constexpr int FM = WTM / 16, FN = WTN / 16;
  constexpr int NT = KD / BK;
  auto As = (u16(*)[BM][BK])smem;
  auto Bs = (u16(*)[BN][BK])(smem + 2 * BM * BK * 2);
  const int tid = threadIdx.x;
  const int bm = ((id & 7) + 8 * ((id >> 3) / NGRP)) * BM;
  const int bn = ((id >> 3) % NGRP) * BN;
  const int l = tid & 63, wid = tid >> 6;
  const int wr = wid >> 2, wc = wid & 3;
  const int lq = l & 15, lg = l >> 4;

  __syncthreads();  // previous smem use (epilogue / prior stage) done

  auto stage = [&](int buf, int k0) {
#pragma unroll
    for (int i = 0; i < (BM * 8 + NTH - 1) / NTH; ++i) {
      const int p = tid + i * NTH;
      if (BM * 8 % NTH == 0 || p < BM * 8) {
        const int row = p >> 3, ch = p & 7;
        gload16(&A[(size_t)(bm + row) * KD + k0 + ((ch ^ (row & 7)) << 3)],
                &As[buf][row][ch << 3]);
      }
    }
#pragma unroll
    for (int i = 0; i < (BN * 8 + NTH - 1) / NTH; ++i) {
      const int p = tid + i * NTH;
      if (BN * 8 % NTH == 0 || p < BN * 8) {
        const int row = p >> 3, ch = p & 7;
        gload16(&Wt[(size_t)(bn + row) * KD + k0 + ((ch ^ (row & 7)) << 3)],
                &Bs[buf][row][ch << 3]);
      }
    }
  };

  fx4 acc[FM][FN] = {};
  stage(0, 0);
  int cur = 0;
  for (int t = 0; t < NT; ++t) {
    __syncthreads();
    if (t + 1 < NT) stage(cur ^ 1, (t + 1) * BK);
#pragma unroll
    for (int kk = 0; kk < BK; kk += 32) {
      sx8 aF[FM], bF[FN];
#pragma unroll
      for (int m = 0; m < FM; ++m) {
        const int row = wr * WTM + m * 16 + lq;
        aF[m] = *(const sx8*)&As[cur][row][((((kk >> 3) + lg) ^ (row & 7)) << 3)];
      }
#pragma unroll
      for (int n = 0; n < FN; ++n) {
        const int row = wc * WTN + n * 16 + lq;
        bF[n] = *(const sx8*)&Bs[cur][row][((((kk >> 3) + lg) ^ (row & 7)) << 3)];
      }
#pragma unroll
      for (int m = 0; m < FM; ++m)
#pragma unroll
        for (int n = 0; n < FN; ++n) acc[m][n] = mfma32(aF[m], bF[n], acc[m][n]);
    }
    cur ^= 1;
  }

  __syncthreads();  // all LDS reads done; reuse smem as C tile
  if (OP == 1) {
    auto C = (float(*)[BN + 8])smem;
#pragma unroll
    for (int m = 0; m < FM; ++m)
#pragma unroll
      for (int n = 0; n < FN; ++n) {
        const int col = wc * WTN + n * 16 + lq;
        const float bv = bias[bn + col];
#pragma unroll
        for (int r = 0; r < 4; ++r)
          C[wr * WTM + m * 16 + lg * 4 + r][col] = acc[m][n][r] + bv;
      }
    __syncthreads();
    constexpr int CH = (BM * BN / 4) / NTH;
#pragma unroll
    for (int i = 0; i < CH; ++i) {
      const int t = tid + i * NTH;
      const int row = t / (BN / 4), c = t % (BN / 4);
      fx4 v = *(const fx4*)&C[row][c * 4];
      v += *(const fx4*)&resid[(size_t)(bm + row) * ND + bn + c * 4];
      *(fx4*)&((float*)outp)[(size_t)(bm + row) * ND + bn + c * 4] = v;
    }
  } else {
    auto C = (u16(*)[BN + 8])smem;
#pragma unroll
    for (int m = 0; m < FM; ++m)
#pragma unroll
      for (int n = 0; n < FN; ++n) {
        const int col = wc * WTN + n * 16 + lq;
        const float bv = bias[bn + col];
#pragma unroll
        for (int r = 0; r < 4; ++r) {
          float v = acc[m][n][r] + bv;
          if (OP == 2) v = 0.5f * v * (1.0f + erff(v * 0.70710678118654752f));
          C[wr * WTM + m * 16 + lg * 4 + r][col] = f2b(v);
        }
      }
    __syncthreads();
    constexpr int CH = (BM * BN / 8) / NTH;
#pragma unroll
    for (int i = 0; i < CH; ++i) {
      const int t = tid + i * NTH;
      const int row = t / (BN / 8), c = t % (BN / 8);
      *(sx8*)&((u16*)outp)[(size_t)(bm + row) * ND + bn + c * 8] = *(const sx8*)&C[row][c * 8];
    }
  }
}

// ---- banded flash attention body, 128-q tiles, one-pass softmax ----
static __device__ __forceinline__ void attn_body(char* smem, int blk,
                                                 const u16* __restrict__ qkv,
                                                 u16* __restrict__ o) {
  auto Qs = (u16(*)[32])smem;            // [128][32]
  auto Ks = (u16(*)[32])(smem + 8192);   // [256][32]
  auto Vs = (u16(*)[264])(smem + 24576); // [32][264]
  const int tile = blk & 15;
  const int bh = blk >> 4;
  const int h = bh & 7;
  const int b = bh >> 3;
  const int q0 = tile << 7;
  const int kstart = max(0, q0 - 64);
  const int kend = min(T_SEQ, q0 + 192);
  const int nk = kend - kstart;
  const int tid = threadIdx.x;
  const float scale = 0.17677669529663687f;  // 1/sqrt(32)

  __syncthreads();
  {
    const int r = tid >> 2, c8 = (tid & 3) << 3;
    gload16(&qkv[(size_t)(b * T_SEQ + q0 + r) * 768 + h * 32 + c8], &Qs[r][c8]);
  }
  for (int r0 = 0; r0 < nk; r0 += 128) {
    const int r = r0 + (tid >> 2);
    if (r < nk) {
      const int c8 = (tid & 3) << 3;
      gload16(&qkv[(size_t)(b * T_SEQ + kstart + r) * 768 + 256 + h * 32 + c8], &Ks[r][c8]);
    }
  }
  for (int e = tid * 4; e < nk * 32; e += 2048) {
    const int r = e >> 5, c = e & 31;
    sx4 v = *(const sx4*)&qkv[(size_t)(b * T_SEQ + kstart + r) * 768 + 512 + h * 32 + c];
    Vs[c + 0][r] = v[0];
    Vs[c + 1][r] = v[1];
    Vs[c + 2][r] = v[2];
    Vs[c + 3][r] = v[3];
  }
  __syncthreads();

  const int w = tid >> 6, l = tid & 63;
  const int lq = l & 15, lg = l >> 4;
  const int qw0 = q0 + w * 16;
  const int iq = qw0 + lq;
  const sx8 qB = *(const sx8*)&Qs[w * 16 + lq][8 * lg];
  float lsum = 0.0f;
  fx4 acc0 = {0.f, 0.f, 0.f, 0.f}, acc1 = {0.f, 0.f, 0.f, 0.f};
  const int rt0 = max(0, qw0 - 64 - kstart) >> 4;
  const int rt1 = (min(kend, qw0 + 80) - kstart) >> 4;
  for (int rt = rt0; rt < rt1; ++rt) {
    const int kb = kstart + (rt << 4);
    const sx8 kA = *(const sx8*)&Ks[(rt << 4) + lq][8 * lg];
    fx4 zero = {0.f, 0.f, 0.f, 0.f};
    fx4 sc = mfma32(kA, qB, zero);
    sx4 pB;
#pragma unroll
    for (int r = 0; r < 4; ++r) {
      const int dd = kb + 4 * lg + r - iq;
      const float sv = (dd >= -64 && dd <= 64) ? fminf(sc[r] * scale, 30.0f) : -100.0f;
      const float p = __expf(sv);
      lsum += p;
      pB[r] = (short)f2b(p);
    }
    const sx4 vA0 = *(const sx4*)&Vs[lq][(rt << 4) + 4 * lg];
    const sx4 vA1 = *(const sx4*)&Vs[16 + lq][(rt << 4) + 4 * lg];
    acc0 = mfma16(vA0, pB, acc0);
    acc1 = mfma16(vA1, pB, acc1);
  }
  lsum += __shfl_xor(lsum, 16);
  lsum += __shfl_xor(lsum, 32);
  const float rl = 1.0f / lsum;

  __syncthreads();
  auto Os = (u16(*)[32])Qs;
#pragma unroll
  for (int r = 0; r < 4; ++r) {
    Os[w * 16 + lq][4 * lg + r] = f2b(acc0[r] * rl);
    Os[w * 16 + lq][16 + 4 * lg + r] = f2b(acc1[r] * rl);
  }
  __syncthreads();
  {
    const int row = tid >> 2, c = tid & 3;
    *(sx8*)&o[(size_t)(b * T_SEQ + q0 + row) * 256 + h * 32 + c * 8] =
        *(const sx8*)&Os[row][c * 8];
  }
}

// ---- fused out-proj + bias + x-residual(bf16) + LN2 body (16 rows) ----
static __device__ __forceinline__ void gemmln_body(char* smem, int bid,
                                                   const u16* __restrict__ A,
                                                   const u16* __restrict__ Wt,
                                                   const float* __restrict__ bias,
                                                   const u16* __restrict__ xb,
                                                   const float* __restrict__ g,
                                                   const float* __restrict__ bv2,
                                                   u16* __restrict__ yn) {
  auto As = (u16(*)[16][64])smem;              // [2][16][64]
  auto Bs = (u16(*)[256][64])(smem + 4096);    // [2][256][64]
  auto red = (float(*)[8][2])(smem + 69632);   // [16][8][2]
  auto Ys = (u16(*)[264])smem;                 // [16][264] (aliases As/Bs)
  const int tid = threadIdx.x;
  const int bm = bid * 16;
  const int l = tid & 63, wc = tid >> 6;       // 8 waves, all wr=0
  const int lq = l & 15, lg = l >> 4;

  __syncthreads();

  auto stage = [&](int buf, int k0) {
    if (tid < 128) {
      const int row = tid >> 3, ch = tid & 7;
      gload16(&A[(size_t)(bm + row) * 256 + k0 + ((ch ^ (row & 7)) << 3)],
              &As[buf][row][ch << 3]);
    }
#pragma unroll
    for (int i = 0; i < 4; ++i) {
      const int p = tid + i * 512;
      const int row = p >> 3, ch = p & 7;
      gload16(&Wt[(size_t)row * 256 + k0 + ((ch ^ (row & 7)) << 3)],
              &Bs[buf][row][ch << 3]);
    }
  };

  fx4 acc[2] = {};
  stage(0, 0);
  int cur = 0;
  for (int t = 0; t < 4; ++t) {
    __syncthreads();
    if (t + 1 < 4) stage(cur ^ 1, (t + 1) * 64);
#pragma unroll
    for (int kk = 0; kk < 64; kk += 32) {
      const sx8 aF = *(const sx8*)&As[cur][lq][((((kk >> 3) + lg) ^ (lq & 7)) << 3)];
#pragma unroll
      for (int n = 0; n < 2; ++n) {
        const int brow = wc * 32 + n * 16 + lq;
        const sx8 bF = *(const sx8*)&Bs[cur][brow][((((kk >> 3) + lg) ^ (brow & 7)) << 3)];
        acc[n] = mfma32(aF, bF, acc[n]);
      }
    }
    cur ^= 1;
  }

  float vv[2][4];
  float s[4] = {}, q[4] = {};
#pragma unroll
  for (int n = 0; n < 2; ++n) {
    const int col = wc * 32 + n * 16 + lq;
    const float bb = bias[col];
#pragma unroll
    for (int r = 0; r < 4; ++r) {
      const int row = bm + lg * 4 + r;
      const float v = acc[n][r] + bb + b2f(xb[(size_t)row * 256 + col]);
      vv[n][r] = v;
      s[r] += v;
      q[r] += v * v;
    }
  }
#pragma unroll
  for (int off = 1; off < 16; off <<= 1) {
#pragma unroll
    for (int r = 0; r < 4; ++r) {
      s[r] += __shfl_xor(s[r], off);
      q[r] += __shfl_xor(q[r], off);
    }
  }
  __syncthreads();
  if (lq == 0) {
#pragma unroll
    for (int r = 0; r < 4; ++r) {
      red[lg * 4 + r][wc][0] = s[r];
      red[lg * 4 + r][wc][1] = q[r];
    }
  }
  __syncthreads();
  float mean4[4], rs4[4];
#pragma unroll
  for (int r = 0; r < 4; ++r) {
    const int rr = lg * 4 + r;
    float st = 0.f, qt = 0.f;
#pragma unroll
    for (int w8 = 0; w8 < 8; ++w8) {
      st += red[rr][w8][0];
      qt += red[rr][w8][1];
    }
    mean4[r] = st * (1.0f / 256.0f);
    const float var = qt * (1.0f / 256.0f) - mean4[r] * mean4[r];
    rs4[r] = rsqrtf(var + 1e-5f);
  }
  __syncthreads();
#pragma unroll
  for (int n = 0; n < 2; ++n) {
    const int col = wc * 32 + n * 16 + lq;
    const float gc = g[col], bc = bv2[col];
#pragma unroll
    for (int r = 0; r < 4; ++r)
      Ys[lg * 4 + r][col] = f2b((vv[n][r] - mean4[r]) * rs4[r] * gc + bc);
  }
  __syncthreads();
  {
    const int row = tid >> 5, c = tid & 31;
    *(sx8*)&yn[(size_t)(bm + row) * 256 + c * 8] = *(const sx8*)&Ys[row][c * 8];
  }
}

// =========================== megakernel =====================================
struct MegaArgs {
  const float *x, *ln1g, *ln1b, *ipw, *ipb, *outw, *outb, *ln2g, *ln2b, *w1, *b1, *w2, *b2;
  u16 *xn, *xb, *qkvb, *o, *yn, *hh, *ipwT, *outwT, *w1T, *w2T;
  float* out;
};

__global__ __launch_bounds__(512, 4) void mega_k(MegaArgs a) {
  __shared__ __align__(16) char smem[70656];
  cg::grid_group grid = cg::this_grid();
  const int bid = blockIdx.x, tid = threadIdx.x;

  // ---- stage 0: LN1 + x->bf16 (16 rows/block) + weight transposes ----
  {
    const int l = tid & 63, wv = tid >> 6;
#pragma unroll
    for (int p = 0; p < 2; ++p) {
      const int row = bid * 16 + p * 8 + wv;
      fx4 v = *(const fx4*)&a.x[(size_t)row * 256 + l * 4];
      float s = v.x + v.y + v.z + v.w;
      float q = v.x * v.x + v.y * v.y + v.z * v.z + v.w * v.w;
#pragma unroll
      for (int off = 1; off < 64; off <<= 1) {
        s += __shfl_xor(s, off);
        q += __shfl_xor(q, off);
      }
      const float mean = s * (1.0f / 256.0f);
      const float var = q * (1.0f / 256.0f) - mean * mean;
      const float rstd = rsqrtf(var + 1e-5f);
      fx4 gv = *(const fx4*)&a.ln1g[l * 4];
      fx4 bv = *(const fx4*)&a.ln1b[l * 4];
      sx4 o_, xo;
      o_[0] = (short)f2b((v.x - mean) * rstd * gv.x + bv.x);
      o_[1] = (short)f2b((v.y - mean) * rstd * gv.y + bv.y);
      o_[2] = (short)f2b((v.z - mean) * rstd * gv.z + bv.z);
      o_[3] = (short)f2b((v.w - mean) * rstd * gv.w + bv.w);
      xo[0] = (short)f2b(v.x);
      xo[1] = (short)f2b(v.y);
      xo[2] = (short)f2b(v.z);
      xo[3] = (short)f2b(v.w);
      *(sx4*)&a.xn[(size_t)row * 256 + l * 4] = o_;
      *(sx4*)&a.xb[(size_t)row * 256 + l * 4] = xo;
    }
    auto tt = (float(*)[33])smem;
    for (int tb = bid; tb < 768; tb += 512) {
      const float* in; u16* outp; int K, N, loc;
      if (tb < 192)      { in = a.ipw;  outp = a.ipwT;  K = 256;  N = 768;  loc = tb; }
      else if (tb < 256) { in = a.outw; outp = a.outwT; K = 256;  N = 256;  loc = tb - 192; }
      else if (tb < 512) { in = a.w1;   outp = a.w1T;   K = 256;  N = 1024; loc = tb - 256; }
      else               { in = a.w2;   outp = a.w2T;   K = 1024; N = 256;  loc = tb - 512; }
      const int ntx = N >> 5;
      const int by = (loc / ntx) << 5;
      const int bx = (loc % ntx) << 5;
      const int c = tid & 31, r0 = tid >> 5;  // r0 in 0..15
      __syncthreads();
#pragma unroll
      for (int i = 0; i < 2; ++i)
        tt[r0 + i * 16][c] = in[(size_t)(by + r0 + i * 16) * N + bx + c];
      __syncthreads();
#pragma unroll
      for (int i = 0; i < 2; ++i) {
        const int r = r0 + i * 16;
        outp[(size_t)(bx + r) * K + by + c] = f2b(tt[c][r]);
      }
    }
  }
  __threadfence();
  grid.sync();

  // ---- stage 1: qkv projection (768 tiles over 512 blocks) ----
  for (int t1 = bid; t1 < 768; t1 += 512)
    gemm_body<64, 128, 256, 768, 0, 6>(smem, t1, a.xn, a.ipwT, a.ipb, nullptr, a.qkvb);
  __threadfence();
  grid.sync();

  // ---- stage 2: banded attention ----
  attn_body(smem, bid, a.qkvb, a.o);
  __threadfence();
  grid.sync();

  // ---- stage 3: out-proj + residual + LN2 ----
  gemmln_body(smem, bid, a.o, a.outwT, a.outb, a.xb, a.ln2g, a.ln2b, a.yn);
  __threadfence();
  grid.sync();

  // ---- stage 4: ff1 + GELU ----
  gemm_body<128, 128, 256, 1024, 2, 8>(smem, bid, a.yn, a.w1T, a.b1, nullptr, a.hh);
  __threadfence();
  grid.sync();

  // ---- stage 5: ff2 + bias + x residual ----
  gemm_body<32, 128, 1024, 256, 1, 2>(smem, bid, a.hh, a.w2T, a.b2, a.x, a.out);
}

// =================== fallback wrappers (R11 proven path) ====================
__global__ __launch_bounds__(256) void prep_k(
    const float* __restrict__ x, const float* __restrict__ g1,
    const float* __restrict__ b1, u16* __restrict__ xn, u16* __restrict__ xb,
    const float* __restrict__ ipw, const float* __restrict__ outw,
    const float* __restrict__ w1, const float* __restrict__ w2,
    u16* __restrict__ ipwT, u16* __restrict__ outwT,
    u16* __restrict__ w1T, u16* __restrict__ w2T) {
  const int bid = blockIdx.x;
  if (bid < 2048) {
    const int row = bid * 4 + (threadIdx.x >> 6);
    const int l = threadIdx.x & 63;
    fx4 v = *(const fx4*)&x[(size_t)row * 256 + l * 4];
    float s = v.x + v.y + v.z + v.w;
    float q = v.x * v.x + v.y * v.y + v.z * v.z + v.w * v.w;
#pragma unroll
    for (int off = 1; off < 64; off <<= 1) {
      s += __shfl_xor(s, off);
      q += __shfl_xor(q, off);
    }
    const float mean = s * (1.0f / 256.0f);
    const float var = q * (1.0f / 256.0f) - mean * mean;
    const float rstd = rsqrtf(var + 1e-5f);
    fx4 gv = *(const fx4*)&g1[l * 4];
    fx4 bv = *(const fx4*)&b1[l * 4];
    sx4 o, xo;
    o[0] = (short)f2b((v.x - mean) * rstd * gv.x + bv.x);
    o[1] = (short)f2b((v.y - mean) * rstd * gv.y + bv.y);
    o[2] = (short)f2b((v.z - mean) * rstd * gv.z + bv.z);
    o[3] = (short)f2b((v.w - mean) * rstd * gv.w + bv.w);
    xo[0] = (short)f2b(v.x);
    xo[1] = (short)f2b(v.y);
    xo[2] = (short)f2b(v.z);
    xo[3] = (short)f2b(v.w);
    *(sx4*)&xn[(size_t)row * 256 + l * 4] = o;
    *(sx4*)&xb[(size_t)row * 256 + l * 4] = xo;
    return;
  }
  const int tb = bid - 2048;
  const float* in; u16* out; int K, N, loc;
  if (tb < 192)      { in = ipw;  out = ipwT;  K = 256;  N = 768;  loc = tb; }
  else if (tb < 256) { in = outw; out = outwT; K = 256;  N = 256;  loc = tb - 192; }
  else if (tb < 512) { in = w1;   out = w1T;   K = 256;  N = 1024; loc = tb - 256; }
  else               { in = w2;   out = w2T;   K = 1024; N = 256;  loc = tb - 512; }
  const int ntx = N >> 5;
  const int by = (loc / ntx) << 5;
  const int bx = (loc % ntx) << 5;
  __shared__ float t[32][33];
  const int c = threadIdx.x & 31, r0 = threadIdx.x >> 5;
#pragma unroll
  for (int i = 0; i < 4; ++i)
    t[r0 + i * 8][c] = in[(size_t)(by + r0 + i * 8) * N + bx + c];
  __syncthreads();
#pragma unroll
  for (int i = 0; i < 4; ++i) {
    const int r = r0 + i * 8;
    out[(size_t)(bx + r) * K + by + c] = f2b(t[c][r]);
  }
}

template <int BM, int BN, int KD, int ND, int OP, int NGRP>
__global__ __launch_bounds__(512) void gemm6_k(const u16* __restrict__ A,
                                               const u16* __restrict__ Wt,
                                               const float* __restrict__ bias,
                                               const float* __restrict__ resid,
                                               void* __restrict__ outp) {
  __shared__ __align__(16) char smem[(2 * BM + 2 * BN) * 64 * 2];
  gemm_body<BM, BN, KD, ND, OP, NGRP>(smem, blockIdx.x, A, Wt, bias, resid, outp);
}

__global__ __launch_bounds__(512) void gemmln_k(const u16* __restrict__ A,
                                                const u16* __restrict__ Wt,
                                                const float* __restrict__ bias,
                                                const u16* __restrict__ xb,
                                                const float* __restrict__ g,
                                                const float* __restrict__ bv2,
                                                u16* __restrict__ yn) {
  __shared__ __align__(16) char smem[70656];
  gemmln_body(smem, blockIdx.x, A, Wt, bias, xb, g, bv2, yn);
}

__global__ __launch_bounds__(512) void attn_k(const u16* __restrict__ qkv,
                                              u16* __restrict__ o) {
  __shared__ __align__(16) char smem[41472];
  attn_body(smem, blockIdx.x, qkv, o);
}

extern "C" void kernel_launch(void* const* d_in, const int* in_sizes, int n_in,
                              void* d_out, int out_size, void* d_ws, size_t ws_size,
                              hipStream_t stream) {
  const float* x    = (const float*)d_in[0];
  const float* ln1g = (const float*)d_in[1];
  const float* ln1b = (const float*)d_in[2];
  const float* ipw  = (const float*)d_in[3];
  const float* ipb  = (const float*)d_in[4];
  const float* outw = (const float*)d_in[5];
  const float* outb = (const float*)d_in[6];
  const float* ln2g = (const float*)d_in[7];
  const float* ln2b = (const float*)d_in[8];
  const float* w1   = (const float*)d_in[9];
  const float* b1   = (const float*)d_in[10];
  const float* w2   = (const float*)d_in[11];
  const float* b2   = (const float*)d_in[12];

  char* ws = (char*)d_ws;
  u16*   xn   = (u16*)(ws);                          // 4 MB  bf16 [8192][256]
  u16*   qkvb = (u16*)(ws + (4ull << 20));           // 12 MB bf16 [8192][768]
  u16*   o    = (u16*)(ws + (16ull << 20));          // 4 MB  bf16 [8192][256]
  u16*   yn   = (u16*)(ws + (20ull << 20));          // 4 MB  bf16 [8192][256]
  u16*   hh   = (u16*)(ws + (24ull << 20));          // 16 MB bf16 [8192][1024]
  u16*   xb   = (u16*)(ws + (40ull << 20));          // 4 MB  bf16 [8192][256]
  u16*   ipwT = (u16*)(ws + (44ull << 20));          // 384 KB bf16 [768][256]
  u16*   outwT= (u16*)(ws + (44ull << 20) + (512ull << 10));   // 128 KB [256][256]
  u16*   w1T  = (u16*)(ws + (45ull << 20));          // 512 KB bf16 [1024][256]
  u16*   w2T  = (u16*)(ws + (45ull << 20) + (512ull << 10));   // 512 KB [256][1024]

  MegaArgs a;
  a.x = x; a.ln1g = ln1g; a.ln1b = ln1b; a.ipw = ipw; a.ipb = ipb;
  a.outw = outw; a.outb = outb; a.ln2g = ln2g; a.ln2b = ln2b;
  a.w1 = w1; a.b1 = b1; a.w2 = w2; a.b2 = b2;
  a.xn = xn; a.xb = xb; a.qkvb = qkvb; a.o = o; a.yn = yn; a.hh = hh;
  a.ipwT = ipwT; a.outwT = outwT; a.w1T = w1T; a.w2T = w2T;
  a.out = (float*)d_out;

  void* kargs[] = {(void*)&a};
  hipError_t err = hipLaunchCooperativeKernel((void*)mega_k, dim3(512), dim3(512),
                                              kargs, 0, stream);
  if (err != hipSuccess) {
    // fallback: proven 6-kernel path
    prep_k<<<2816, 256, 0, stream>>>(x, ln1g, ln1b, xn, xb, ipw, outw, w1, w2,
                                     ipwT, outwT, w1T, w2T);
    gemm6_k<64, 128, 256, 768, 0, 6><<<768, 512, 0, stream>>>(xn, ipwT, ipb, nullptr, qkvb);
    attn_k<<<512, 512, 0, stream>>>(qkvb, o);
    gemmln_k<<<512, 512, 0, stream>>>(o, outwT, outb, xb, ln2g, ln2b, yn);
    gemm6_k<128, 128, 256, 1024, 2, 8><<<512, 512, 0, stream>>>(yn, w1T, b1, nullptr, hh);
    gemm6_k<32, 128, 1024, 256, 1, 2><<<512, 512, 0, stream>>>(hh, w2T, b2, x, (float*)d_out);
  }
}

// Round 14
// 59.559 us; speedup vs baseline: 12.8421x; 12.8331x over previous
//
#include <hip/hip_runtime.h>
#include <math.h>

#define T_SEQ 2048

typedef float  fx4 __attribute__((ext_vector_type(4)));
typedef short  sx4 __attribute__((ext_vector_type(4)));
typedef short  sx8 __attribute__((ext_vector_type(8)));
typedef unsigned short u16;

static __device__ __forceinline__ u16 f2b(float f) {
  unsigned u = __builtin_bit_cast(unsigned, f);
  u += 0x7fffu + ((u >> 16) & 1u);   // RNE
  return (u16)(u >> 16);
}
static __device__ __forceinline__ float b2f(u16 v) {
  unsigned u = ((unsigned)v) << 16;
  return __builtin_bit_cast(float, u);
}

static __device__ __forceinline__ fx4 mfma16(sx4 a, sx4 b, fx4 c) {
  return __builtin_amdgcn_mfma_f32_16x16x16bf16_1k(a, b, c, 0, 0, 0);
}
static __device__ __forceinline__ fx4 mfma32(sx8 a, sx8 b, fx4 c) {
  return __builtin_amdgcn_mfma_f32_16x16x32_bf16(a, b, c, 0, 0, 0);
}

static __device__ __forceinline__ void gload16(const void* g, void* l) {
  __builtin_amdgcn_global_load_lds(
      (const __attribute__((address_space(1))) unsigned*)g,
      (__attribute__((address_space(3))) unsigned*)l, 16, 0, 0);
}

// -- prep: LN1 + x->bf16 (blocks 0..2047) + ipw transpose (2048..2239) -------
__global__ __launch_bounds__(256) void prep_k(
    const float* __restrict__ x, const float* __restrict__ g1,
    const float* __restrict__ b1, u16* __restrict__ xn, u16* __restrict__ xb,
    const float* __restrict__ ipw, u16* __restrict__ ipwT) {
  const int bid = blockIdx.x;
  if (bid < 2048) {
    const int row = bid * 4 + (threadIdx.x >> 6);
    const int l = threadIdx.x & 63;
    fx4 v = *(const fx4*)&x[(size_t)row * 256 + l * 4];
    float s = v.x + v.y + v.z + v.w;
    float q = v.x * v.x + v.y * v.y + v.z * v.z + v.w * v.w;
#pragma unroll
    for (int off = 1; off < 64; off <<= 1) {
      s += __shfl_xor(s, off);
      q += __shfl_xor(q, off);
    }
    const float mean = s * (1.0f / 256.0f);
    const float var = q * (1.0f / 256.0f) - mean * mean;
    const float rstd = rsqrtf(var + 1e-5f);
    fx4 gv = *(const fx4*)&g1[l * 4];
    fx4 bv = *(const fx4*)&b1[l * 4];
    sx4 o, xo;
    o[0] = (short)f2b((v.x - mean) * rstd * gv.x + bv.x);
    o[1] = (short)f2b((v.y - mean) * rstd * gv.y + bv.y);
    o[2] = (short)f2b((v.z - mean) * rstd * gv.z + bv.z);
    o[3] = (short)f2b((v.w - mean) * rstd * gv.w + bv.w);
    xo[0] = (short)f2b(v.x);
    xo[1] = (short)f2b(v.y);
    xo[2] = (short)f2b(v.z);
    xo[3] = (short)f2b(v.w);
    *(sx4*)&xn[(size_t)row * 256 + l * 4] = o;
    *(sx4*)&xb[(size_t)row * 256 + l * 4] = xo;
    return;
  }
  // ipw transpose: f32 [256][768] -> bf16 [768][256]
  const int loc = bid - 2048;          // 0..191
  const int by = (loc / 24) << 5;      // k base
  const int bx = (loc % 24) << 5;      // n base
  __shared__ float t[32][33];
  const int c = threadIdx.x & 31, r0 = threadIdx.x >> 5;
#pragma unroll
  for (int i = 0; i < 4; ++i)
    t[r0 + i * 8][c] = ipw[(size_t)(by + r0 + i * 8) * 768 + bx + c];
  __syncthreads();
#pragma unroll
  for (int i = 0; i < 4; ++i) {
    const int r = r0 + i * 8;
    ipwT[(size_t)(bx + r) * 256 + by + c] = f2b(t[c][r]);
  }
}

// ---- GEMM: 512 threads (2x4 waves), BK=64 dbuf, XOR-swizzled LDS,
//      XCD-grouped decode, coalesced epilogue via LDS C-tile.
// OP: 0 = store bf16, 1 = +resid store f32, 2 = exact-GELU store bf16,
//     3 = qkv head-major split store bf16 (qh/kh/vh)
template <int BM, int BN, int KD, int ND, int OP, int NGRP>
__global__ __launch_bounds__(512) void gemm6_k(const u16* __restrict__ A,
                                               const u16* __restrict__ Wt,
                                               const float* __restrict__ bias,
                                               const float* __restrict__ resid,
                                               void* __restrict__ outp,
                                               u16* __restrict__ qh,
                                               u16* __restrict__ kh,
                                               u16* __restrict__ vh) {
  constexpr int BK = 64;
  constexpr int NTH = 512;
  constexpr int WTM = BM / 2, WTN = BN / 4;
  constexpr int FM = WTM / 16, FN = WTN / 16;
  constexpr int NT = KD / BK;
  __shared__ __align__(16) char smem[(2 * BM + 2 * BN) * BK * 2];
  auto As = (u16(*)[BM][BK])smem;
  auto Bs = (u16(*)[BN][BK])(smem + 2 * BM * BK * 2);
  const int tid = threadIdx.x;
  const int id = blockIdx.x;
  const int bm = ((id & 7) + 8 * ((id >> 3) / NGRP)) * BM;
  const int bn = ((id >> 3) % NGRP) * BN;
  const int l = tid & 63, wid = tid >> 6;
  const int wr = wid >> 2, wc = wid & 3;
  const int lq = l & 15, lg = l >> 4;

  auto stage = [&](int buf, int k0) {
#pragma unroll
    for (int i = 0; i < (BM * 8 + NTH - 1) / NTH; ++i) {
      const int p = tid + i * NTH;
      if (BM * 8 % NTH == 0 || p < BM * 8) {
        const int row = p >> 3, ch = p & 7;
        gload16(&A[(size_t)(bm + row) * KD + k0 + ((ch ^ (row & 7)) << 3)],
                &As[buf][row][ch << 3]);
      }
    }
#pragma unroll
    for (int i = 0; i < (BN * 8 + NTH - 1) / NTH; ++i) {
      const int p = tid + i * NTH;
      if (BN * 8 % NTH == 0 || p < BN * 8) {
        const int row = p >> 3, ch = p & 7;
        gload16(&Wt[(size_t)(bn + row) * KD + k0 + ((ch ^ (row & 7)) << 3)],
                &Bs[buf][row][ch << 3]);
      }
    }
  };

  fx4 acc[FM][FN] = {};
  stage(0, 0);
  int cur = 0;
  for (int t = 0; t < NT; ++t) {
    __syncthreads();
    if (t + 1 < NT) stage(cur ^ 1, (t + 1) * BK);
#pragma unroll
    for (int kk = 0; kk < BK; kk += 32) {
      sx8 aF[FM], bF[FN];
#pragma unroll
      for (int m = 0; m < FM; ++m) {
        const int row = wr * WTM + m * 16 + lq;
        aF[m] = *(const sx8*)&As[cur][row][((((kk >> 3) + lg) ^ (row & 7)) << 3)];
      }
#pragma unroll
      for (int n = 0; n < FN; ++n) {
        const int row = wc * WTN + n * 16 + lq;
        bF[n] = *(const sx8*)&Bs[cur][row][((((kk >> 3) + lg) ^ (row & 7)) << 3)];
      }
#pragma unroll
      for (int m = 0; m < FM; ++m)
#pragma unroll
        for (int n = 0; n < FN; ++n) acc[m][n] = mfma32(aF[m], bF[n], acc[m][n]);
    }
    cur ^= 1;
  }

  __syncthreads();  // all LDS reads done; reuse smem as C tile
  if (OP == 1) {
    auto C = (float(*)[BN + 8])smem;
#pragma unroll
    for (int m = 0; m < FM; ++m)
#pragma unroll
      for (int n = 0; n < FN; ++n) {
        const int col = wc * WTN + n * 16 + lq;
        const float bv = bias[bn + col];
#pragma unroll
        for (int r = 0; r < 4; ++r)
          C[wr * WTM + m * 16 + lg * 4 + r][col] = acc[m][n][r] + bv;
      }
    __syncthreads();
    constexpr int CH = (BM * BN / 4) / NTH;
#pragma unroll
    for (int i = 0; i < CH; ++i) {
      const int t = tid + i * NTH;
      const int row = t / (BN / 4), c = t % (BN / 4);
      fx4 v = *(const fx4*)&C[row][c * 4];
      v += *(const fx4*)&resid[(size_t)(bm + row) * ND + bn + c * 4];
      *(fx4*)&((float*)outp)[(size_t)(bm + row) * ND + bn + c * 4] = v;
    }
  } else {
    auto C = (u16(*)[BN + 8])smem;
#pragma unroll
    for (int m = 0; m < FM; ++m)
#pragma unroll
      for (int n = 0; n < FN; ++n) {
        const int col = wc * WTN + n * 16 + lq;
        const float bv = bias[bn + col];
#pragma unroll
        for (int r = 0; r < 4; ++r) {
          float v = acc[m][n][r] + bv;
          if (OP == 2) v = 0.5f * v * (1.0f + erff(v * 0.70710678118654752f));
          C[wr * WTM + m * 16 + lg * 4 + r][col] = f2b(v);
        }
      }
    __syncthreads();
    constexpr int CH = (BM * BN / 8) / NTH;
#pragma unroll
    for (int i = 0; i < CH; ++i) {
      const int t = tid + i * NTH;
      const int row = t / (BN / 8), c = t % (BN / 8);
      if (OP == 3) {
        // head-major split: q|k|v each [b*8+h][2048][32]
        const int n = bn + c * 8;
        const int sect = n >> 8, within = n & 255;
        const int head = within >> 5, d = within & 31;
        const int grow = bm + row;
        const int b = grow >> 11, tt = grow & 2047;
        u16* dst = sect == 0 ? qh : (sect == 1 ? kh : vh);
        *(sx8*)&dst[(((size_t)(b * 8 + head) * 2048 + tt) << 5) + d] =
            *(const sx8*)&C[row][c * 8];
      } else {
        *(sx8*)&((u16*)outp)[(size_t)(bm + row) * ND + bn + c * 8] = *(const sx8*)&C[row][c * 8];
      }
    }
  }
}

// ------- Fused out-proj + bias + x-residual(bf16) + LayerNorm2 -> yn bf16 ----
// 16 rows/block, 512 threads (1x8 wave grid), BK=64 dbuf, swizzled LDS.
__global__ __launch_bounds__(512) void gemmln_k(const u16* __restrict__ A,
                                                const u16* __restrict__ Wt,
                                                const float* __restrict__ bias,
                                                const u16* __restrict__ xb,
                                                const float* __restrict__ g,
                                                const float* __restrict__ bv2,
                                                u16* __restrict__ yn) {
  __shared__ __align__(16) char smem[70656];
  auto As = (u16(*)[16][64])smem;              // [2][16][64]
  auto Bs = (u16(*)[256][64])(smem + 4096);    // [2][256][64]
  auto red = (float(*)[8][2])(smem + 69632);   // [16][8][2]
  auto Ys = (u16(*)[264])smem;                 // [16][264] (aliases As/Bs)
  const int tid = threadIdx.x;
  const int bm = blockIdx.x * 16;
  const int l = tid & 63, wc = tid >> 6;       // 8 waves, all wr=0
  const int lq = l & 15, lg = l >> 4;

  auto stage = [&](int buf, int k0) {
    if (tid < 128) {
      const int row = tid >> 3, ch = tid & 7;
      gload16(&A[(size_t)(bm + row) * 256 + k0 + ((ch ^ (row & 7)) << 3)],
              &As[buf][row][ch << 3]);
    }
#pragma unroll
    for (int i = 0; i < 4; ++i) {
      const int p = tid + i * 512;
      const int row = p >> 3, ch = p & 7;
      gload16(&Wt[(size_t)row * 256 + k0 + ((ch ^ (row & 7)) << 3)],
              &Bs[buf][row][ch << 3]);
    }
  };

  fx4 acc[2] = {};
  stage(0, 0);
  int cur = 0;
  for (int t = 0; t < 4; ++t) {
    __syncthreads();
    if (t + 1 < 4) stage(cur ^ 1, (t + 1) * 64);
#pragma unroll
    for (int kk = 0; kk < 64; kk += 32) {
      const sx8 aF = *(const sx8*)&As[cur][lq][((((kk >> 3) + lg) ^ (lq & 7)) << 3)];
#pragma unroll
      for (int n = 0; n < 2; ++n) {
        const int brow = wc * 32 + n * 16 + lq;
        const sx8 bF = *(const sx8*)&Bs[cur][brow][((((kk >> 3) + lg) ^ (brow & 7)) << 3)];
        acc[n] = mfma32(aF, bF, acc[n]);
      }
    }
    cur ^= 1;
  }

  float vv[2][4];
  float s[4] = {}, q[4] = {};
#pragma unroll
  for (int n = 0; n < 2; ++n) {
    const int col = wc * 32 + n * 16 + lq;
    const float bb = bias[col];
#pragma unroll
    for (int r = 0; r < 4; ++r) {
      const int row = bm + lg * 4 + r;
      const float v = acc[n][r] + bb + b2f(xb[(size_t)row * 256 + col]);
      vv[n][r] = v;
      s[r] += v;
      q[r] += v * v;
    }
  }
#pragma unroll
  for (int off = 1; off < 16; off <<= 1) {
#pragma unroll
    for (int r = 0; r < 4; ++r) {
      s[r] += __shfl_xor(s[r], off);
      q[r] += __shfl_xor(q[r], off);
    }
  }
  __syncthreads();
  if (lq == 0) {
#pragma unroll
    for (int r = 0; r < 4; ++r) {
      red[lg * 4 + r][wc][0] = s[r];
      red[lg * 4 + r][wc][1] = q[r];
    }
  }
  __syncthreads();
  float mean4[4], rs4[4];
#pragma unroll
  for (int r = 0; r < 4; ++r) {
    const int rr = lg * 4 + r;
    float st = 0.f, qt = 0.f;
#pragma unroll
    for (int w8 = 0; w8 < 8; ++w8) {
      st += red[rr][w8][0];
      qt += red[rr][w8][1];
    }
    mean4[r] = st * (1.0f / 256.0f);
    const float var = qt * (1.0f / 256.0f) - mean4[r] * mean4[r];
    rs4[r] = rsqrtf(var + 1e-5f);
  }
  __syncthreads();
#pragma unroll
  for (int n = 0; n < 2; ++n) {
    const int col = wc * 32 + n * 16 + lq;
    const float gc = g[col], bc = bv2[col];
#pragma unroll
    for (int r = 0; r < 4; ++r)
      Ys[lg * 4 + r][col] = f2b((vv[n][r] - mean4[r]) * rs4[r] * gc + bc);
  }
  __syncthreads();
  {
    const int row = tid >> 5, c = tid & 31;
    *(sx8*)&yn[(size_t)(bm + row) * 256 + c * 8] = *(const sx8*)&Ys[row][c * 8];
  }
}

// ---- Banded flash attention (head-major q/k/v) + piggybacked transposes ----
// blocks 0..511: attention (128-q tiles, one-pass softmax).
// blocks 512..1087: outw/w1/w2 transposes (needed 1-3 stages later).
__global__ __launch_bounds__(512) void attn_k(const u16* __restrict__ qh,
                                              const u16* __restrict__ kh,
                                              const u16* __restrict__ vh,
                                              u16* __restrict__ o,
                                              const float* __restrict__ outw,
                                              const float* __restrict__ w1,
                                              const float* __restrict__ w2,
                                              u16* __restrict__ outwT,
                                              u16* __restrict__ w1T,
                                              u16* __restrict__ w2T) {
  __shared__ __align__(16) char smem[41728];
  const int blk = blockIdx.x;
  const int tid = threadIdx.x;

  if (blk >= 512) {  // ---- weight transpose path ----
    const int tb = blk - 512;
    const float* in; u16* out; int K, N, loc;
    if (tb < 64)       { in = outw; out = outwT; K = 256;  N = 256;  loc = tb; }
    else if (tb < 320) { in = w1;   out = w1T;   K = 256;  N = 1024; loc = tb - 64; }
    else               { in = w2;   out = w2T;   K = 1024; N = 256;  loc = tb - 320; }
    const int ntx = N >> 5;
    const int by = (loc / ntx) << 5;
    const int bx = (loc % ntx) << 5;
    auto t = (float(*)[33])smem;
    const int c = tid & 31, r0 = tid >> 5;  // r0 in 0..15
#pragma unroll
    for (int i = 0; i < 2; ++i)
      t[r0 + i * 16][c] = in[(size_t)(by + r0 + i * 16) * N + bx + c];
    __syncthreads();
#pragma unroll
    for (int i = 0; i < 2; ++i) {
      const int r = r0 + i * 16;
      out[(size_t)(bx + r) * K + by + c] = f2b(t[c][r]);
    }
    return;
  }

  auto Qs = (u16(*)[32])smem;             // [128][32]
  auto Ks = (u16(*)[32])(smem + 8192);    // [256][32]
  auto Vs = (u16(*)[268])(smem + 24576);  // [32][268] transposed: Vs[d][key]
  const int tile = blk & 15;
  const int bh = blk >> 4;                // b*8 + h
  const int q0 = tile << 7;
  const int kstart = max(0, q0 - 64);
  const int kend = min(T_SEQ, q0 + 192);
  const int nk = kend - kstart;
  const float scale = 0.17677669529663687f;  // 1/sqrt(32)
  const size_t hbase = (size_t)bh * T_SEQ;

  {  // Q: 128 rows x 64B, dense head-major
    const int r = tid >> 2, c8 = (tid & 3) << 3;
    gload16(&qh[((hbase + q0 + r) << 5) + c8], &Qs[r][c8]);
  }
  for (int r0 = 0; r0 < nk; r0 += 128) {
    const int r = r0 + (tid >> 2);
    if (r < nk) {
      const int c8 = (tid & 3) << 3;
      gload16(&kh[((hbase + kstart + r) << 5) + c8], &Ks[r][c8]);
    }
  }
  for (int e = tid * 4; e < nk * 32; e += 2048) {
    const int r = e >> 5, c = e & 31;
    sx4 v = *(const sx4*)&vh[((hbase + kstart + r) << 5) + c];
    Vs[c + 0][r] = v[0];
    Vs[c + 1][r] = v[1];
    Vs[c + 2][r] = v[2];
    Vs[c + 3][r] = v[3];
  }
  __syncthreads();

  const int w = tid >> 6, l = tid & 63;
  const int lq = l & 15, lg = l >> 4;
  const int qw0 = q0 + w * 16;
  const int iq = qw0 + lq;
  const sx8 qB = *(const sx8*)&Qs[w * 16 + lq][8 * lg];
  float lsum = 0.0f;
  fx4 acc0 = {0.f, 0.f, 0.f, 0.f}, acc1 = {0.f, 0.f, 0.f, 0.f};
  const int rt0 = max(0, qw0 - 64 - kstart) >> 4;
  const int rt1 = (min(kend, qw0 + 80) - kstart) >> 4;
  for (int rt = rt0; rt < rt1; ++rt) {
    const int kb = kstart + (rt << 4);
    const sx8 kA = *(const sx8*)&Ks[(rt << 4) + lq][8 * lg];
    fx4 zero = {0.f, 0.f, 0.f, 0.f};
    fx4 sc = mfma32(kA, qB, zero);
    sx4 pB;
#pragma unroll
    for (int r = 0; r < 4; ++r) {
      const int dd = kb + 4 * lg + r - iq;
      const float sv = (dd >= -64 && dd <= 64) ? fminf(sc[r] * scale, 30.0f) : -100.0f;
      const float p = __expf(sv);
      lsum += p;
      pB[r] = (short)f2b(p);
    }
    const sx4 vA0 = *(const sx4*)&Vs[lq][(rt << 4) + 4 * lg];
    const sx4 vA1 = *(const sx4*)&Vs[16 + lq][(rt << 4) + 4 * lg];
    acc0 = mfma16(vA0, pB, acc0);
    acc1 = mfma16(vA1, pB, acc1);
  }
  lsum += __shfl_xor(lsum, 16);
  lsum += __shfl_xor(lsum, 32);
  const float rl = 1.0f / lsum;

  __syncthreads();
  auto Os = (u16(*)[32])Qs;
#pragma unroll
  for (int r = 0; r < 4; ++r) {
    Os[w * 16 + lq][4 * lg + r] = f2b(acc0[r] * rl);
    Os[w * 16 + lq][16 + 4 * lg + r] = f2b(acc1[r] * rl);
  }
  __syncthreads();
  {
    // o stays row-major [8192][256] for the out-proj GEMM
    const int b = bh >> 3, h = bh & 7;
    const int row = tid >> 2, c = tid & 3;
    *(sx8*)&o[(size_t)(b * T_SEQ + q0 + row) * 256 + h * 32 + c * 8] =
        *(const sx8*)&Os[row][c * 8];
  }
}

extern "C" void kernel_launch(void* const* d_in, const int* in_sizes, int n_in,
                              void* d_out, int out_size, void* d_ws, size_t ws_size,
                              hipStream_t stream) {
  const float* x    = (const float*)d_in[0];
  const float* ln1g = (const float*)d_in[1];
  const float* ln1b = (const float*)d_in[2];
  const float* ipw  = (const float*)d_in[3];
  const float* ipb  = (const float*)d_in[4];
  const float* outw = (const float*)d_in[5];
  const float* outb = (const float*)d_in[6];
  const float* ln2g = (const float*)d_in[7];
  const float* ln2b = (const float*)d_in[8];
  const float* w1   = (const float*)d_in[9];
  const float* b1   = (const float*)d_in[10];
  const float* w2   = (const float*)d_in[11];
  const float* b2   = (const float*)d_in[12];

  char* ws = (char*)d_ws;
  u16*   xn   = (u16*)(ws);                          // 4 MB  bf16 [8192][256]
  u16*   qh   = (u16*)(ws + (4ull << 20));           // 4 MB  bf16 [32][2048][32]
  u16*   kh   = (u16*)(ws + (8ull << 20));           // 4 MB
  u16*   vh   = (u16*)(ws + (12ull << 20));          // 4 MB
  u16*   o    = (u16*)(ws + (16ull << 20));          // 4 MB  bf16 [8192][256]
  u16*   yn   = (u16*)(ws + (20ull << 20));          // 4 MB  bf16 [8192][256]
  u16*   hh   = (u16*)(ws + (24ull << 20));          // 16 MB bf16 [8192][1024]
  u16*   xb   = (u16*)(ws + (40ull << 20));          // 4 MB  bf16 [8192][256]
  u16*   ipwT = (u16*)(ws + (44ull << 20));          // 384 KB bf16 [768][256]
  u16*   outwT= (u16*)(ws + (44ull << 20) + (512ull << 10));   // 128 KB [256][256]
  u16*   w1T  = (u16*)(ws + (45ull << 20));          // 512 KB bf16 [1024][256]
  u16*   w2T  = (u16*)(ws + (45ull << 20) + (512ull << 10));   // 512 KB [256][1024]

  prep_k<<<2240, 256, 0, stream>>>(x, ln1g, ln1b, xn, xb, ipw, ipwT);
  gemm6_k<64, 128, 256, 768, 3, 6><<<768, 512, 0, stream>>>(
      xn, ipwT, ipb, nullptr, nullptr, qh, kh, vh);
  attn_k<<<1088, 512, 0, stream>>>(qh, kh, vh, o, outw, w1, w2, outwT, w1T, w2T);
  gemmln_k<<<512, 512, 0, stream>>>(o, outwT, outb, xb, ln2g, ln2b, yn);
  gemm6_k<128, 128, 256, 1024, 2, 8><<<512, 512, 0, stream>>>(
      yn, w1T, b1, nullptr, hh, nullptr, nullptr, nullptr);
  gemm6_k<32, 128, 1024, 256, 1, 2><<<512, 512, 0, stream>>>(
      hh, w2T, b2, x, (float*)d_out, nullptr, nullptr, nullptr);
}

// Round 15
// 59.517 us; speedup vs baseline: 12.8513x; 1.0007x over previous
//
#include <hip/hip_runtime.h>
#include <math.h>

#define T_SEQ 2048

typedef float  fx4 __attribute__((ext_vector_type(4)));
typedef short  sx4 __attribute__((ext_vector_type(4)));
typedef short  sx8 __attribute__((ext_vector_type(8)));
typedef unsigned short u16;

static __device__ __forceinline__ u16 f2b(float f) {
  unsigned u = __builtin_bit_cast(unsigned, f);
  u += 0x7fffu + ((u >> 16) & 1u);   // RNE
  return (u16)(u >> 16);
}
static __device__ __forceinline__ float b2f(u16 v) {
  unsigned u = ((unsigned)v) << 16;
  return __builtin_bit_cast(float, u);
}

static __device__ __forceinline__ fx4 mfma16(sx4 a, sx4 b, fx4 c) {
  return __builtin_amdgcn_mfma_f32_16x16x16bf16_1k(a, b, c, 0, 0, 0);
}
static __device__ __forceinline__ fx4 mfma32(sx8 a, sx8 b, fx4 c) {
  return __builtin_amdgcn_mfma_f32_16x16x32_bf16(a, b, c, 0, 0, 0);
}

static __device__ __forceinline__ void gload16(const void* g, void* l) {
  __builtin_amdgcn_global_load_lds(
      (const __attribute__((address_space(1))) unsigned*)g,
      (__attribute__((address_space(3))) unsigned*)l, 16, 0, 0);
}

// -- prep: LN1 + x->bf16 (blocks 0..2047) + ipw transpose (2048..2239) -------
__global__ __launch_bounds__(256) void prep_k(
    const float* __restrict__ x, const float* __restrict__ g1,
    const float* __restrict__ b1, u16* __restrict__ xn, u16* __restrict__ xb,
    const float* __restrict__ ipw, u16* __restrict__ ipwT) {
  const int bid = blockIdx.x;
  if (bid < 2048) {
    const int row = bid * 4 + (threadIdx.x >> 6);
    const int l = threadIdx.x & 63;
    fx4 v = *(const fx4*)&x[(size_t)row * 256 + l * 4];
    float s = v.x + v.y + v.z + v.w;
    float q = v.x * v.x + v.y * v.y + v.z * v.z + v.w * v.w;
#pragma unroll
    for (int off = 1; off < 64; off <<= 1) {
      s += __shfl_xor(s, off);
      q += __shfl_xor(q, off);
    }
    const float mean = s * (1.0f / 256.0f);
    const float var = q * (1.0f / 256.0f) - mean * mean;
    const float rstd = rsqrtf(var + 1e-5f);
    fx4 gv = *(const fx4*)&g1[l * 4];
    fx4 bv = *(const fx4*)&b1[l * 4];
    sx4 o, xo;
    o[0] = (short)f2b((v.x - mean) * rstd * gv.x + bv.x);
    o[1] = (short)f2b((v.y - mean) * rstd * gv.y + bv.y);
    o[2] = (short)f2b((v.z - mean) * rstd * gv.z + bv.z);
    o[3] = (short)f2b((v.w - mean) * rstd * gv.w + bv.w);
    xo[0] = (short)f2b(v.x);
    xo[1] = (short)f2b(v.y);
    xo[2] = (short)f2b(v.z);
    xo[3] = (short)f2b(v.w);
    *(sx4*)&xn[(size_t)row * 256 + l * 4] = o;
    *(sx4*)&xb[(size_t)row * 256 + l * 4] = xo;
    return;
  }
  // ipw transpose: f32 [256][768] -> bf16 [768][256]
  const int loc = bid - 2048;          // 0..191
  const int by = (loc / 24) << 5;      // k base
  const int bx = (loc % 24) << 5;      // n base
  __shared__ float t[32][33];
  const int c = threadIdx.x & 31, r0 = threadIdx.x >> 5;
#pragma unroll
  for (int i = 0; i < 4; ++i)
    t[r0 + i * 8][c] = ipw[(size_t)(by + r0 + i * 8) * 768 + bx + c];
  __syncthreads();
#pragma unroll
  for (int i = 0; i < 4; ++i) {
    const int r = r0 + i * 8;
    ipwT[(size_t)(bx + r) * 256 + by + c] = f2b(t[c][r]);
  }
}

// ---- GEMM: 512 threads (2x4 waves), BK=64 dbuf, XOR-swizzled LDS,
//      XCD-grouped decode, coalesced epilogue via LDS C-tile.
// OP: 0 = store bf16, 1 = +resid store f32, 2 = exact-GELU store bf16,
//     3 = qkv head-major split store bf16 (qh/kh/vh)
template <int BM, int BN, int KD, int ND, int OP, int NGRP>
__global__ __launch_bounds__(512) void gemm6_k(const u16* __restrict__ A,
                                               const u16* __restrict__ Wt,
                                               const float* __restrict__ bias,
                                               const float* __restrict__ resid,
                                               void* __restrict__ outp,
                                               u16* __restrict__ qh,
                                               u16* __restrict__ kh,
                                               u16* __restrict__ vh) {
  constexpr int BK = 64;
  constexpr int NTH = 512;
  constexpr int WTM = BM / 2, WTN = BN / 4;
  constexpr int FM = WTM / 16, FN = WTN / 16;
  constexpr int NT = KD / BK;
  __shared__ __align__(16) char smem[(2 * BM + 2 * BN) * BK * 2];
  auto As = (u16(*)[BM][BK])smem;
  auto Bs = (u16(*)[BN][BK])(smem + 2 * BM * BK * 2);
  const int tid = threadIdx.x;
  const int id = blockIdx.x;
  const int bm = ((id & 7) + 8 * ((id >> 3) / NGRP)) * BM;
  const int bn = ((id >> 3) % NGRP) * BN;
  const int l = tid & 63, wid = tid >> 6;
  const int wr = wid >> 2, wc = wid & 3;
  const int lq = l & 15, lg = l >> 4;

  auto stage = [&](int buf, int k0) {
#pragma unroll
    for (int i = 0; i < (BM * 8 + NTH - 1) / NTH; ++i) {
      const int p = tid + i * NTH;
      if (BM * 8 % NTH == 0 || p < BM * 8) {
        const int row = p >> 3, ch = p & 7;
        gload16(&A[(size_t)(bm + row) * KD + k0 + ((ch ^ (row & 7)) << 3)],
                &As[buf][row][ch << 3]);
      }
    }
#pragma unroll
    for (int i = 0; i < (BN * 8 + NTH - 1) / NTH; ++i) {
      const int p = tid + i * NTH;
      if (BN * 8 % NTH == 0 || p < BN * 8) {
        const int row = p >> 3, ch = p & 7;
        gload16(&Wt[(size_t)(bn + row) * KD + k0 + ((ch ^ (row & 7)) << 3)],
                &Bs[buf][row][ch << 3]);
      }
    }
  };

  fx4 acc[FM][FN] = {};
  stage(0, 0);
  int cur = 0;
  for (int t = 0; t < NT; ++t) {
    __syncthreads();
    if (t + 1 < NT) stage(cur ^ 1, (t + 1) * BK);
#pragma unroll
    for (int kk = 0; kk < BK; kk += 32) {
      sx8 aF[FM], bF[FN];
#pragma unroll
      for (int m = 0; m < FM; ++m) {
        const int row = wr * WTM + m * 16 + lq;
        aF[m] = *(const sx8*)&As[cur][row][((((kk >> 3) + lg) ^ (row & 7)) << 3)];
      }
#pragma unroll
      for (int n = 0; n < FN; ++n) {
        const int row = wc * WTN + n * 16 + lq;
        bF[n] = *(const sx8*)&Bs[cur][row][((((kk >> 3) + lg) ^ (row & 7)) << 3)];
      }
#pragma unroll
      for (int m = 0; m < FM; ++m)
#pragma unroll
        for (int n = 0; n < FN; ++n) acc[m][n] = mfma32(aF[m], bF[n], acc[m][n]);
    }
    cur ^= 1;
  }

  __syncthreads();  // all LDS reads done; reuse smem as C tile
  if (OP == 1) {
    auto C = (float(*)[BN + 8])smem;
#pragma unroll
    for (int m = 0; m < FM; ++m)
#pragma unroll
      for (int n = 0; n < FN; ++n) {
        const int col = wc * WTN + n * 16 + lq;
        const float bv = bias[bn + col];
#pragma unroll
        for (int r = 0; r < 4; ++r)
          C[wr * WTM + m * 16 + lg * 4 + r][col] = acc[m][n][r] + bv;
      }
    __syncthreads();
    constexpr int CH = (BM * BN / 4) / NTH;
#pragma unroll
    for (int i = 0; i < CH; ++i) {
      const int t = tid + i * NTH;
      const int row = t / (BN / 4), c = t % (BN / 4);
      fx4 v = *(const fx4*)&C[row][c * 4];
      v += *(const fx4*)&resid[(size_t)(bm + row) * ND + bn + c * 4];
      *(fx4*)&((float*)outp)[(size_t)(bm + row) * ND + bn + c * 4] = v;
    }
  } else {
    auto C = (u16(*)[BN + 8])smem;
#pragma unroll
    for (int m = 0; m < FM; ++m)
#pragma unroll
      for (int n = 0; n < FN; ++n) {
        const int col = wc * WTN + n * 16 + lq;
        const float bv = bias[bn + col];
#pragma unroll
        for (int r = 0; r < 4; ++r) {
          float v = acc[m][n][r] + bv;
          if (OP == 2) v = 0.5f * v * (1.0f + erff(v * 0.70710678118654752f));
          C[wr * WTM + m * 16 + lg * 4 + r][col] = f2b(v);
        }
      }
    __syncthreads();
    constexpr int CH = (BM * BN / 8) / NTH;
#pragma unroll
    for (int i = 0; i < CH; ++i) {
      const int t = tid + i * NTH;
      const int row = t / (BN / 8), c = t % (BN / 8);
      if (OP == 3) {
        // head-major split: q|k|v each [b*8+h][2048][32]
        const int n = bn + c * 8;
        const int sect = n >> 8, within = n & 255;
        const int head = within >> 5, d = within & 31;
        const int grow = bm + row;
        const int b = grow >> 11, tt = grow & 2047;
        u16* dst = sect == 0 ? qh : (sect == 1 ? kh : vh);
        *(sx8*)&dst[(((size_t)(b * 8 + head) * 2048 + tt) << 5) + d] =
            *(const sx8*)&C[row][c * 8];
      } else {
        *(sx8*)&((u16*)outp)[(size_t)(bm + row) * ND + bn + c * 8] = *(const sx8*)&C[row][c * 8];
      }
    }
  }
}

// ------- Fused out-proj + bias + x-residual(bf16) + LayerNorm2 -> yn bf16 ----
// 16 rows/block, 512 threads (1x8 wave grid), BK=64 dbuf, swizzled LDS.
__global__ __launch_bounds__(512) void gemmln_k(const u16* __restrict__ A,
                                                const u16* __restrict__ Wt,
                                                const float* __restrict__ bias,
                                                const u16* __restrict__ xb,
                                                const float* __restrict__ g,
                                                const float* __restrict__ bv2,
                                                u16* __restrict__ yn) {
  __shared__ __align__(16) char smem[70656];
  auto As = (u16(*)[16][64])smem;              // [2][16][64]
  auto Bs = (u16(*)[256][64])(smem + 4096);    // [2][256][64]
  auto red = (float(*)[8][2])(smem + 69632);   // [16][8][2]
  auto Ys = (u16(*)[264])smem;                 // [16][264] (aliases As/Bs)
  const int tid = threadIdx.x;
  const int bm = blockIdx.x * 16;
  const int l = tid & 63, wc = tid >> 6;       // 8 waves, all wr=0
  const int lq = l & 15, lg = l >> 4;

  auto stage = [&](int buf, int k0) {
    if (tid < 128) {
      const int row = tid >> 3, ch = tid & 7;
      gload16(&A[(size_t)(bm + row) * 256 + k0 + ((ch ^ (row & 7)) << 3)],
              &As[buf][row][ch << 3]);
    }
#pragma unroll
    for (int i = 0; i < 4; ++i) {
      const int p = tid + i * 512;
      const int row = p >> 3, ch = p & 7;
      gload16(&Wt[(size_t)row * 256 + k0 + ((ch ^ (row & 7)) << 3)],
              &Bs[buf][row][ch << 3]);
    }
  };

  fx4 acc[2] = {};
  stage(0, 0);
  int cur = 0;
  for (int t = 0; t < 4; ++t) {
    __syncthreads();
    if (t + 1 < 4) stage(cur ^ 1, (t + 1) * 64);
#pragma unroll
    for (int kk = 0; kk < 64; kk += 32) {
      const sx8 aF = *(const sx8*)&As[cur][lq][((((kk >> 3) + lg) ^ (lq & 7)) << 3)];
#pragma unroll
      for (int n = 0; n < 2; ++n) {
        const int brow = wc * 32 + n * 16 + lq;
        const sx8 bF = *(const sx8*)&Bs[cur][brow][((((kk >> 3) + lg) ^ (brow & 7)) << 3)];
        acc[n] = mfma32(aF, bF, acc[n]);
      }
    }
    cur ^= 1;
  }

  float vv[2][4];
  float s[4] = {}, q[4] = {};
#pragma unroll
  for (int n = 0; n < 2; ++n) {
    const int col = wc * 32 + n * 16 + lq;
    const float bb = bias[col];
#pragma unroll
    for (int r = 0; r < 4; ++r) {
      const int row = bm + lg * 4 + r;
      const float v = acc[n][r] + bb + b2f(xb[(size_t)row * 256 + col]);
      vv[n][r] = v;
      s[r] += v;
      q[r] += v * v;
    }
  }
#pragma unroll
  for (int off = 1; off < 16; off <<= 1) {
#pragma unroll
    for (int r = 0; r < 4; ++r) {
      s[r] += __shfl_xor(s[r], off);
      q[r] += __shfl_xor(q[r], off);
    }
  }
  __syncthreads();
  if (lq == 0) {
#pragma unroll
    for (int r = 0; r < 4; ++r) {
      red[lg * 4 + r][wc][0] = s[r];
      red[lg * 4 + r][wc][1] = q[r];
    }
  }
  __syncthreads();
  float mean4[4], rs4[4];
#pragma unroll
  for (int r = 0; r < 4; ++r) {
    const int rr = lg * 4 + r;
    float st = 0.f, qt = 0.f;
#pragma unroll
    for (int w8 = 0; w8 < 8; ++w8) {
      st += red[rr][w8][0];
      qt += red[rr][w8][1];
    }
    mean4[r] = st * (1.0f / 256.0f);
    const float var = qt * (1.0f / 256.0f) - mean4[r] * mean4[r];
    rs4[r] = rsqrtf(var + 1e-5f);
  }
  __syncthreads();
#pragma unroll
  for (int n = 0; n < 2; ++n) {
    const int col = wc * 32 + n * 16 + lq;
    const float gc = g[col], bc = bv2[col];
#pragma unroll
    for (int r = 0; r < 4; ++r)
      Ys[lg * 4 + r][col] = f2b((vv[n][r] - mean4[r]) * rs4[r] * gc + bc);
  }
  __syncthreads();
  {
    const int row = tid >> 5, c = tid & 31;
    *(sx8*)&yn[(size_t)(bm + row) * 256 + c * 8] = *(const sx8*)&Ys[row][c * 8];
  }
}

// ---- Banded flash attention (head-major q/k/v) + piggybacked transposes ----
// blocks 0..511: attention (128-q tiles, one-pass softmax).
// blocks 512..1087: outw/w1/w2 transposes (needed 1-3 stages later).
__global__ __launch_bounds__(512) void attn_k(const u16* __restrict__ qh,
                                              const u16* __restrict__ kh,
                                              const u16* __restrict__ vh,
                                              u16* __restrict__ o,
                                              const float* __restrict__ outw,
                                              const float* __restrict__ w1,
                                              const float* __restrict__ w2,
                                              u16* __restrict__ outwT,
                                              u16* __restrict__ w1T,
                                              u16* __restrict__ w2T) {
  __shared__ __align__(16) char smem[41728];
  const int blk = blockIdx.x;
  const int tid = threadIdx.x;

  if (blk >= 512) {  // ---- weight transpose path ----
    const int tb = blk - 512;
    const float* in; u16* out; int K, N, loc;
    if (tb < 64)       { in = outw; out = outwT; K = 256;  N = 256;  loc = tb; }
    else if (tb < 320) { in = w1;   out = w1T;   K = 256;  N = 1024; loc = tb - 64; }
    else               { in = w2;   out = w2T;   K = 1024; N = 256;  loc = tb - 320; }
    const int ntx = N >> 5;
    const int by = (loc / ntx) << 5;
    const int bx = (loc % ntx) << 5;
    auto t = (float(*)[33])smem;
    const int c = tid & 31, r0 = tid >> 5;  // r0 in 0..15
#pragma unroll
    for (int i = 0; i < 2; ++i)
      t[r0 + i * 16][c] = in[(size_t)(by + r0 + i * 16) * N + bx + c];
    __syncthreads();
#pragma unroll
    for (int i = 0; i < 2; ++i) {
      const int r = r0 + i * 16;
      out[(size_t)(bx + r) * K + by + c] = f2b(t[c][r]);
    }
    return;
  }

  auto Qs = (u16(*)[32])smem;             // [128][32]
  auto Ks = (u16(*)[32])(smem + 8192);    // [256][32]
  auto Vs = (u16(*)[268])(smem + 24576);  // [32][268] transposed: Vs[d][key]
  const int tile = blk & 15;
  const int bh = blk >> 4;                // b*8 + h
  const int q0 = tile << 7;
  const int kstart = max(0, q0 - 64);
  const int kend = min(T_SEQ, q0 + 192);
  const int nk = kend - kstart;
  const float scale = 0.17677669529663687f;  // 1/sqrt(32)
  const size_t hbase = (size_t)bh * T_SEQ;

  {  // Q: 128 rows x 64B, dense head-major
    const int r = tid >> 2, c8 = (tid & 3) << 3;
    gload16(&qh[((hbase + q0 + r) << 5) + c8], &Qs[r][c8]);
  }
  for (int r0 = 0; r0 < nk; r0 += 128) {
    const int r = r0 + (tid >> 2);
    if (r < nk) {
      const int c8 = (tid & 3) << 3;
      gload16(&kh[((hbase + kstart + r) << 5) + c8], &Ks[r][c8]);
    }
  }
  for (int e = tid * 4; e < nk * 32; e += 2048) {
    const int r = e >> 5, c = e & 31;
    sx4 v = *(const sx4*)&vh[((hbase + kstart + r) << 5) + c];
    Vs[c + 0][r] = v[0];
    Vs[c + 1][r] = v[1];
    Vs[c + 2][r] = v[2];
    Vs[c + 3][r] = v[3];
  }
  __syncthreads();

  const int w = tid >> 6, l = tid & 63;
  const int lq = l & 15, lg = l >> 4;
  const int qw0 = q0 + w * 16;
  const int iq = qw0 + lq;
  const sx8 qB = *(const sx8*)&Qs[w * 16 + lq][8 * lg];
  float lsum = 0.0f;
  fx4 acc0 = {0.f, 0.f, 0.f, 0.f}, acc1 = {0.f, 0.f, 0.f, 0.f};
  const int rt0 = max(0, qw0 - 64 - kstart) >> 4;
  const int rt1 = (min(kend, qw0 + 80) - kstart) >> 4;
  for (int rt = rt0; rt < rt1; ++rt) {
    const int kb = kstart + (rt << 4);
    const sx8 kA = *(const sx8*)&Ks[(rt << 4) + lq][8 * lg];
    fx4 zero = {0.f, 0.f, 0.f, 0.f};
    fx4 sc = mfma32(kA, qB, zero);
    sx4 pB;
#pragma unroll
    for (int r = 0; r < 4; ++r) {
      const int dd = kb + 4 * lg + r - iq;
      const float sv = (dd >= -64 && dd <= 64) ? fminf(sc[r] * scale, 30.0f) : -100.0f;
      const float p = __expf(sv);
      lsum += p;
      pB[r] = (short)f2b(p);
    }
    const sx4 vA0 = *(const sx4*)&Vs[lq][(rt << 4) + 4 * lg];
    const sx4 vA1 = *(const sx4*)&Vs[16 + lq][(rt << 4) + 4 * lg];
    acc0 = mfma16(vA0, pB, acc0);
    acc1 = mfma16(vA1, pB, acc1);
  }
  lsum += __shfl_xor(lsum, 16);
  lsum += __shfl_xor(lsum, 32);
  const float rl = 1.0f / lsum;

  __syncthreads();
  auto Os = (u16(*)[32])Qs;
#pragma unroll
  for (int r = 0; r < 4; ++r) {
    Os[w * 16 + lq][4 * lg + r] = f2b(acc0[r] * rl);
    Os[w * 16 + lq][16 + 4 * lg + r] = f2b(acc1[r] * rl);
  }
  __syncthreads();
  {
    // o stays row-major [8192][256] for the out-proj GEMM
    const int b = bh >> 3, h = bh & 7;
    const int row = tid >> 2, c = tid & 3;
    *(sx8*)&o[(size_t)(b * T_SEQ + q0 + row) * 256 + h * 32 + c * 8] =
        *(const sx8*)&Os[row][c * 8];
  }
}

extern "C" void kernel_launch(void* const* d_in, const int* in_sizes, int n_in,
                              void* d_out, int out_size, void* d_ws, size_t ws_size,
                              hipStream_t stream) {
  const float* x    = (const float*)d_in[0];
  const float* ln1g = (const float*)d_in[1];
  const float* ln1b = (const float*)d_in[2];
  const float* ipw  = (const float*)d_in[3];
  const float* ipb  = (const float*)d_in[4];
  const float* outw = (const float*)d_in[5];
  const float* outb = (const float*)d_in[6];
  const float* ln2g = (const float*)d_in[7];
  const float* ln2b = (const float*)d_in[8];
  const float* w1   = (const float*)d_in[9];
  const float* b1   = (const float*)d_in[10];
  const float* w2   = (const float*)d_in[11];
  const float* b2   = (const float*)d_in[12];

  char* ws = (char*)d_ws;
  u16*   xn   = (u16*)(ws);                          // 4 MB  bf16 [8192][256]
  u16*   qh   = (u16*)(ws + (4ull << 20));           // 4 MB  bf16 [32][2048][32]
  u16*   kh   = (u16*)(ws + (8ull << 20));           // 4 MB
  u16*   vh   = (u16*)(ws + (12ull << 20));          // 4 MB
  u16*   o    = (u16*)(ws + (16ull << 20));          // 4 MB  bf16 [8192][256]
  u16*   yn   = (u16*)(ws + (20ull << 20));          // 4 MB  bf16 [8192][256]
  u16*   hh   = (u16*)(ws + (24ull << 20));          // 16 MB bf16 [8192][1024]
  u16*   xb   = (u16*)(ws + (40ull << 20));          // 4 MB  bf16 [8192][256]
  u16*   ipwT = (u16*)(ws + (44ull << 20));          // 384 KB bf16 [768][256]
  u16*   outwT= (u16*)(ws + (44ull << 20) + (512ull << 10));   // 128 KB [256][256]
  u16*   w1T  = (u16*)(ws + (45ull << 20));          // 512 KB bf16 [1024][256]
  u16*   w2T  = (u16*)(ws + (45ull << 20) + (512ull << 10));   // 512 KB [256][1024]

  prep_k<<<2240, 256, 0, stream>>>(x, ln1g, ln1b, xn, xb, ipw, ipwT);
  gemm6_k<64, 128, 256, 768, 3, 6><<<768, 512, 0, stream>>>(
      xn, ipwT, ipb, nullptr, nullptr, qh, kh, vh);
  attn_k<<<1088, 512, 0, stream>>>(qh, kh, vh, o, outw, w1, w2, outwT, w1T, w2T);
  gemmln_k<<<512, 512, 0, stream>>>(o, outwT, outb, xb, ln2g, ln2b, yn);
  gemm6_k<128, 128, 256, 1024, 2, 8><<<512, 512, 0, stream>>>(
      yn, w1T, b1, nullptr, hh, nullptr, nullptr, nullptr);
  gemm6_k<32, 128, 1024, 256, 1, 2><<<512, 512, 0, stream>>>(
      hh, w2T, b2, x, (float*)d_out, nullptr, nullptr, nullptr);
}

// Round 16
// 59.056 us; speedup vs baseline: 12.9516x; 1.0078x over previous
//
#include <hip/hip_runtime.h>
#include <math.h>

#define T_SEQ 2048

typedef float  fx4 __attribute__((ext_vector_type(4)));
typedef short  sx4 __attribute__((ext_vector_type(4)));
typedef short  sx8 __attribute__((ext_vector_type(8)));
typedef unsigned short u16;

static __device__ __forceinline__ u16 f2b(float f) {
  unsigned u = __builtin_bit_cast(unsigned, f);
  u += 0x7fffu + ((u >> 16) & 1u);   // RNE
  return (u16)(u >> 16);
}
static __device__ __forceinline__ float b2f(u16 v) {
  unsigned u = ((unsigned)v) << 16;
  return __builtin_bit_cast(float, u);
}

static __device__ __forceinline__ fx4 mfma16(sx4 a, sx4 b, fx4 c) {
  return __builtin_amdgcn_mfma_f32_16x16x16bf16_1k(a, b, c, 0, 0, 0);
}
static __device__ __forceinline__ fx4 mfma32(sx8 a, sx8 b, fx4 c) {
  return __builtin_amdgcn_mfma_f32_16x16x32_bf16(a, b, c, 0, 0, 0);
}

static __device__ __forceinline__ void gload16(const void* g, void* l) {
  __builtin_amdgcn_global_load_lds(
      (const __attribute__((address_space(1))) unsigned*)g,
      (__attribute__((address_space(3))) unsigned*)l, 16, 0, 0);
}

// -- prep: LN1 + x->bf16 (blocks 0..2047), weight transposes (2048..2815) ----
__global__ __launch_bounds__(256) void prep_k(
    const float* __restrict__ x, const float* __restrict__ g1,
    const float* __restrict__ b1, u16* __restrict__ xn, u16* __restrict__ xb,
    const float* __restrict__ ipw, const float* __restrict__ outw,
    const float* __restrict__ w1, const float* __restrict__ w2,
    u16* __restrict__ ipwT, u16* __restrict__ outwT,
    u16* __restrict__ w1T, u16* __restrict__ w2T) {
  const int bid = blockIdx.x;
  if (bid < 2048) {
    const int row = bid * 4 + (threadIdx.x >> 6);
    const int l = threadIdx.x & 63;
    fx4 v = *(const fx4*)&x[(size_t)row * 256 + l * 4];
    float s = v.x + v.y + v.z + v.w;
    float q = v.x * v.x + v.y * v.y + v.z * v.z + v.w * v.w;
#pragma unroll
    for (int off = 1; off < 64; off <<= 1) {
      s += __shfl_xor(s, off);
      q += __shfl_xor(q, off);
    }
    const float mean = s * (1.0f / 256.0f);
    const float var = q * (1.0f / 256.0f) - mean * mean;
    const float rstd = rsqrtf(var + 1e-5f);
    fx4 gv = *(const fx4*)&g1[l * 4];
    fx4 bv = *(const fx4*)&b1[l * 4];
    sx4 o, xo;
    o[0] = (short)f2b((v.x - mean) * rstd * gv.x + bv.x);
    o[1] = (short)f2b((v.y - mean) * rstd * gv.y + bv.y);
    o[2] = (short)f2b((v.z - mean) * rstd * gv.z + bv.z);
    o[3] = (short)f2b((v.w - mean) * rstd * gv.w + bv.w);
    xo[0] = (short)f2b(v.x);
    xo[1] = (short)f2b(v.y);
    xo[2] = (short)f2b(v.z);
    xo[3] = (short)f2b(v.w);
    *(sx4*)&xn[(size_t)row * 256 + l * 4] = o;
    *(sx4*)&xb[(size_t)row * 256 + l * 4] = xo;
    return;
  }
  const int tb = bid - 2048;
  const float* in; u16* out; int K, N, loc;
  if (tb < 192)      { in = ipw;  out = ipwT;  K = 256;  N = 768;  loc = tb; }
  else if (tb < 256) { in = outw; out = outwT; K = 256;  N = 256;  loc = tb - 192; }
  else if (tb < 512) { in = w1;   out = w1T;   K = 256;  N = 1024; loc = tb - 256; }
  else               { in = w2;   out = w2T;   K = 1024; N = 256;  loc = tb - 512; }
  const int ntx = N >> 5;
  const int by = (loc / ntx) << 5;  // k base
  const int bx = (loc % ntx) << 5;  // n base
  __shared__ float t[32][33];
  const int c = threadIdx.x & 31, r0 = threadIdx.x >> 5;
#pragma unroll
  for (int i = 0; i < 4; ++i)
    t[r0 + i * 8][c] = in[(size_t)(by + r0 + i * 8) * N + bx + c];
  __syncthreads();
#pragma unroll
  for (int i = 0; i < 4; ++i) {
    const int r = r0 + i * 8;
    out[(size_t)(bx + r) * K + by + c] = f2b(t[c][r]);
  }
}

// ---- GEMM: 512 threads (8 waves, 2x4), BK=64 dbuf, XOR-swizzled LDS,
//      XCD-grouped decode, coalesced epilogue via LDS C-tile.
// OP: 0 = store bf16, 1 = +resid store f32, 2 = exact-GELU store bf16
template <int BM, int BN, int KD, int ND, int OP, int NGRP>
__global__ __launch_bounds__(512) void gemm5_k(const u16* __restrict__ A,
                                               const u16* __restrict__ Wt,
                                               const float* __restrict__ bias,
                                               const float* __restrict__ resid,
                                               void* __restrict__ outp) {
  constexpr int BK = 64;
  constexpr int NTH = 512;
  constexpr int WTM = BM / 2, WTN = BN / 4;
  constexpr int FM = WTM / 16, FN = WTN / 16;
  constexpr int NT = KD / BK;
  __shared__ __align__(16) char smem[(2 * BM + 2 * BN) * BK * 2];
  auto As = (u16(*)[BM][BK])smem;
  auto Bs = (u16(*)[BN][BK])(smem + 2 * BM * BK * 2);
  const int tid = threadIdx.x;
  const int id = blockIdx.x;
  const int bm = ((id & 7) + 8 * ((id >> 3) / NGRP)) * BM;
  const int bn = ((id >> 3) % NGRP) * BN;
  const int l = tid & 63, wid = tid >> 6;
  const int wr = wid >> 2, wc = wid & 3;
  const int lq = l & 15, lg = l >> 4;

  auto stage = [&](int buf, int k0) {
#pragma unroll
    for (int i = 0; i < (BM * 8 + NTH - 1) / NTH; ++i) {
      const int p = tid + i * NTH;
      if (BM * 8 % NTH == 0 || p < BM * 8) {
        const int row = p >> 3, ch = p & 7;
        gload16(&A[(size_t)(bm + row) * KD + k0 + ((ch ^ (row & 7)) << 3)],
                &As[buf][row][ch << 3]);
      }
    }
#pragma unroll
    for (int i = 0; i < (BN * 8 + NTH - 1) / NTH; ++i) {
      const int p = tid + i * NTH;
      if (BN * 8 % NTH == 0 || p < BN * 8) {
        const int row = p >> 3, ch = p & 7;
        gload16(&Wt[(size_t)(bn + row) * KD + k0 + ((ch ^ (row & 7)) << 3)],
                &Bs[buf][row][ch << 3]);
      }
    }
  };

  fx4 acc[FM][FN] = {};
  stage(0, 0);
  int cur = 0;
  for (int t = 0; t < NT; ++t) {
    __syncthreads();
    if (t + 1 < NT) stage(cur ^ 1, (t + 1) * BK);
#pragma unroll
    for (int kk = 0; kk < BK; kk += 32) {
      sx8 aF[FM], bF[FN];
#pragma unroll
      for (int m = 0; m < FM; ++m) {
        const int row = wr * WTM + m * 16 + lq;
        aF[m] = *(const sx8*)&As[cur][row][((((kk >> 3) + lg) ^ (row & 7)) << 3)];
      }
#pragma unroll
      for (int n = 0; n < FN; ++n) {
        const int row = wc * WTN + n * 16 + lq;
        bF[n] = *(const sx8*)&Bs[cur][row][((((kk >> 3) + lg) ^ (row & 7)) << 3)];
      }
#pragma unroll
      for (int m = 0; m < FM; ++m)
#pragma unroll
        for (int n = 0; n < FN; ++n) acc[m][n] = mfma32(aF[m], bF[n], acc[m][n]);
    }
    cur ^= 1;
  }

  __syncthreads();  // all LDS reads done; reuse smem as C tile
  if (OP == 1) {
    auto C = (float(*)[BN + 8])smem;
#pragma unroll
    for (int m = 0; m < FM; ++m)
#pragma unroll
      for (int n = 0; n < FN; ++n) {
        const int col = wc * WTN + n * 16 + lq;
        const float bv = bias[bn + col];
#pragma unroll
        for (int r = 0; r < 4; ++r)
          C[wr * WTM + m * 16 + lg * 4 + r][col] = acc[m][n][r] + bv;
      }
    __syncthreads();
    constexpr int CH = (BM * BN / 4) / NTH;
#pragma unroll
    for (int i = 0; i < CH; ++i) {
      const int t = tid + i * NTH;
      const int row = t / (BN / 4), c = t % (BN / 4);
      fx4 v = *(const fx4*)&C[row][c * 4];
      v += *(const fx4*)&resid[(size_t)(bm + row) * ND + bn + c * 4];
      *(fx4*)&((float*)outp)[(size_t)(bm + row) * ND + bn + c * 4] = v;
    }
  } else {
    auto C = (u16(*)[BN + 8])smem;
#pragma unroll
    for (int m = 0; m < FM; ++m)
#pragma unroll
      for (int n = 0; n < FN; ++n) {
        const int col = wc * WTN + n * 16 + lq;
        const float bv = bias[bn + col];
#pragma unroll
        for (int r = 0; r < 4; ++r) {
          float v = acc[m][n][r] + bv;
          if (OP == 2) v = 0.5f * v * (1.0f + erff(v * 0.70710678118654752f));
          C[wr * WTM + m * 16 + lg * 4 + r][col] = f2b(v);
        }
      }
    __syncthreads();
    constexpr int CH = (BM * BN / 8) / NTH;
#pragma unroll
    for (int i = 0; i < CH; ++i) {
      const int t = tid + i * NTH;
      const int row = t / (BN / 8), c = t % (BN / 8);
      *(sx8*)&((u16*)outp)[(size_t)(bm + row) * ND + bn + c * 8] = *(const sx8*)&C[row][c * 8];
    }
  }
}

// ------- Fused out-proj + bias + x-residual(bf16) + LayerNorm2 -> yn bf16 ----
// 32 rows/block, 512 threads (2x4 waves), BK=64 double-buffered, swizzled LDS.
__global__ __launch_bounds__(512) void gemmln_k(const u16* __restrict__ A,
                                                const u16* __restrict__ Wt,
                                                const float* __restrict__ bias,
                                                const u16* __restrict__ xb,
                                                const float* __restrict__ g,
                                                const float* __restrict__ bv2,
                                                u16* __restrict__ yn) {
  __shared__ __align__(16) char smem[74752];
  auto As = (u16(*)[32][64])smem;              // [2][32][64]
  auto Bs = (u16(*)[256][64])(smem + 8192);    // [2][256][64]
  auto red = (float(*)[4][2])(smem + 73728);   // [32][4][2]
  auto Ys = (u16(*)[264])smem;                 // [32][264] (aliases As/Bs)
  const int tid = threadIdx.x;
  const int bm = blockIdx.x * 32;
  const int l = tid & 63, wid = tid >> 6;
  const int wr = wid >> 2, wc = wid & 3;
  const int lq = l & 15, lg = l >> 4;

  auto stage = [&](int buf, int k0) {
    if (tid < 256) {
      const int row = tid >> 3, ch = tid & 7;
      gload16(&A[(size_t)(bm + row) * 256 + k0 + ((ch ^ (row & 7)) << 3)],
              &As[buf][row][ch << 3]);
    }
#pragma unroll
    for (int i = 0; i < 4; ++i) {
      const int p = tid + i * 512;
      const int row = p >> 3, ch = p & 7;
      gload16(&Wt[(size_t)row * 256 + k0 + ((ch ^ (row & 7)) << 3)],
              &Bs[buf][row][ch << 3]);
    }
  };

  fx4 acc[4] = {};
  stage(0, 0);
  int cur = 0;
  for (int t = 0; t < 4; ++t) {
    __syncthreads();
    if (t + 1 < 4) stage(cur ^ 1, (t + 1) * 64);
#pragma unroll
    for (int kk = 0; kk < 64; kk += 32) {
      const int arow = wr * 16 + lq;
      const sx8 aF = *(const sx8*)&As[cur][arow][((((kk >> 3) + lg) ^ (arow & 7)) << 3)];
#pragma unroll
      for (int n = 0; n < 4; ++n) {
        const int brow = wc * 64 + n * 16 + lq;
        const sx8 bF = *(const sx8*)&Bs[cur][brow][((((kk >> 3) + lg) ^ (brow & 7)) << 3)];
        acc[n] = mfma32(aF, bF, acc[n]);
      }
    }
    cur ^= 1;
  }

  float vv[4][4];
  float s[4] = {}, q[4] = {};
#pragma unroll
  for (int n = 0; n < 4; ++n) {
    const int col = wc * 64 + n * 16 + lq;
    const float bb = bias[col];
#pragma unroll
    for (int r = 0; r < 4; ++r) {
      const int row = bm + wr * 16 + lg * 4 + r;
      const float v = acc[n][r] + bb + b2f(xb[(size_t)row * 256 + col]);
      vv[n][r] = v;
      s[r] += v;
      q[r] += v * v;
    }
  }
#pragma unroll
  for (int off = 1; off < 16; off <<= 1) {
#pragma unroll
    for (int r = 0; r < 4; ++r) {
      s[r] += __shfl_xor(s[r], off);
      q[r] += __shfl_xor(q[r], off);
    }
  }
  __syncthreads();  // all fragment reads done (also orders red writes)
  if (lq == 0) {
#pragma unroll
    for (int r = 0; r < 4; ++r) {
      red[wr * 16 + lg * 4 + r][wc][0] = s[r];
      red[wr * 16 + lg * 4 + r][wc][1] = q[r];
    }
  }
  __syncthreads();
  float mean4[4], rs4[4];
#pragma unroll
  for (int r = 0; r < 4; ++r) {
    const int rr = wr * 16 + lg * 4 + r;
    const float st = red[rr][0][0] + red[rr][1][0] + red[rr][2][0] + red[rr][3][0];
    const float qt = red[rr][0][1] + red[rr][1][1] + red[rr][2][1] + red[rr][3][1];
    mean4[r] = st * (1.0f / 256.0f);
    const float var = qt * (1.0f / 256.0f) - mean4[r] * mean4[r];
    rs4[r] = rsqrtf(var + 1e-5f);
  }
  __syncthreads();  // safe to overwrite As/Bs region with Ys
#pragma unroll
  for (int n = 0; n < 4; ++n) {
    const int col = wc * 64 + n * 16 + lq;
    const float gc = g[col], bc = bv2[col];
#pragma unroll
    for (int r = 0; r < 4; ++r)
      Ys[wr * 16 + lg * 4 + r][col] = f2b((vv[n][r] - mean4[r]) * rs4[r] * gc + bc);
  }
  __syncthreads();
#pragma unroll
  for (int i = 0; i < 2; ++i) {
    const int t = tid + i * 512;
    const int row = t >> 5, c = t & 31;
    *(sx8*)&yn[(size_t)(bm + row) * 256 + c * 8] = *(const sx8*)&Ys[row][c * 8];
  }
}

// ---------------- Banded flash attention, 128-q tiles, one-pass softmax ------
// Vs stride 268 u16 (134 dwords, gcd(6,32)=2): V-scatter bank conflict
// halved vs 264 (PMC evidence: R13 mega_k 1.2M SQ_LDS_BANK_CONFLICT).
__global__ __launch_bounds__(512) void attn_k(const u16* __restrict__ qkv,
                                              u16* __restrict__ o) {
  __shared__ u16 Qs[128][32];
  __shared__ u16 Ks[256][32];
  __shared__ u16 Vs[32][268];  // transposed: Vs[d][key]
  const int blk = blockIdx.x;
  const int tile = blk & 15;
  const int bh = blk >> 4;
  const int h = bh & 7;
  const int b = bh >> 3;
  const int q0 = tile << 7;
  const int kstart = max(0, q0 - 64);
  const int kend = min(T_SEQ, q0 + 192);
  const int nk = kend - kstart;
  const int tid = threadIdx.x;
  const float scale = 0.17677669529663687f;  // 1/sqrt(32)

  {
    const int r = tid >> 2, c8 = (tid & 3) << 3;
    gload16(&qkv[(size_t)(b * T_SEQ + q0 + r) * 768 + h * 32 + c8], &Qs[r][c8]);
  }
  for (int r0 = 0; r0 < nk; r0 += 128) {
    const int r = r0 + (tid >> 2);
    if (r < nk) {
      const int c8 = (tid & 3) << 3;
      gload16(&qkv[(size_t)(b * T_SEQ + kstart + r) * 768 + 256 + h * 32 + c8], &Ks[r][c8]);
    }
  }
  for (int e = tid * 4; e < nk * 32; e += 2048) {
    const int r = e >> 5, c = e & 31;
    sx4 v = *(const sx4*)&qkv[(size_t)(b * T_SEQ + kstart + r) * 768 + 512 + h * 32 + c];
    Vs[c + 0][r] = v[0];
    Vs[c + 1][r] = v[1];
    Vs[c + 2][r] = v[2];
    Vs[c + 3][r] = v[3];
  }
  __syncthreads();

  const int w = tid >> 6, l = tid & 63;
  const int lq = l & 15, lg = l >> 4;
  const int qw0 = q0 + w * 16;
  const int iq = qw0 + lq;
  const sx8 qB = *(const sx8*)&Qs[w * 16 + lq][8 * lg];
  float lsum = 0.0f;
  fx4 acc0 = {0.f, 0.f, 0.f, 0.f}, acc1 = {0.f, 0.f, 0.f, 0.f};
  const int rt0 = max(0, qw0 - 64 - kstart) >> 4;
  const int rt1 = (min(kend, qw0 + 80) - kstart) >> 4;
  for (int rt = rt0; rt < rt1; ++rt) {
    const int kb = kstart + (rt << 4);
    const sx8 kA = *(const sx8*)&Ks[(rt << 4) + lq][8 * lg];
    fx4 zero = {0.f, 0.f, 0.f, 0.f};
    fx4 sc = mfma32(kA, qB, zero);
    sx4 pB;
#pragma unroll
    for (int r = 0; r < 4; ++r) {
      const int dd = kb + 4 * lg + r - iq;
      const float sv = (dd >= -64 && dd <= 64) ? fminf(sc[r] * scale, 30.0f) : -100.0f;
      const float p = __expf(sv);
      lsum += p;
      pB[r] = (short)f2b(p);
    }
    const sx4 vA0 = *(const sx4*)&Vs[lq][(rt << 4) + 4 * lg];
    const sx4 vA1 = *(const sx4*)&Vs[16 + lq][(rt << 4) + 4 * lg];
    acc0 = mfma16(vA0, pB, acc0);
    acc1 = mfma16(vA1, pB, acc1);
  }
  lsum += __shfl_xor(lsum, 16);
  lsum += __shfl_xor(lsum, 32);
  const float rl = 1.0f / lsum;

  __syncthreads();
  auto Os = (u16(*)[32])Qs;
#pragma unroll
  for (int r = 0; r < 4; ++r) {
    Os[w * 16 + lq][4 * lg + r] = f2b(acc0[r] * rl);
    Os[w * 16 + lq][16 + 4 * lg + r] = f2b(acc1[r] * rl);
  }
  __syncthreads();
  {
    const int row = tid >> 2, c = tid & 3;
    *(sx8*)&o[(size_t)(b * T_SEQ + q0 + row) * 256 + h * 32 + c * 8] =
        *(const sx8*)&Os[row][c * 8];
  }
}

extern "C" void kernel_launch(void* const* d_in, const int* in_sizes, int n_in,
                              void* d_out, int out_size, void* d_ws, size_t ws_size,
                              hipStream_t stream) {
  const float* x    = (const float*)d_in[0];
  const float* ln1g = (const float*)d_in[1];
  const float* ln1b = (const float*)d_in[2];
  const float* ipw  = (const float*)d_in[3];
  const float* ipb  = (const float*)d_in[4];
  const float* outw = (const float*)d_in[5];
  const float* outb = (const float*)d_in[6];
  const float* ln2g = (const float*)d_in[7];
  const float* ln2b = (const float*)d_in[8];
  const float* w1   = (const float*)d_in[9];
  const float* b1   = (const float*)d_in[10];
  const float* w2   = (const float*)d_in[11];
  const float* b2   = (const float*)d_in[12];

  char* ws = (char*)d_ws;
  u16*   xn   = (u16*)(ws);                          // 4 MB  bf16 [8192][256]
  u16*   qkvb = (u16*)(ws + (4ull << 20));           // 12 MB bf16 [8192][768]
  u16*   o    = (u16*)(ws + (16ull << 20));          // 4 MB  bf16 [8192][256]
  u16*   yn   = (u16*)(ws + (20ull << 20));          // 4 MB  bf16 [8192][256]
  u16*   hh   = (u16*)(ws + (24ull << 20));          // 16 MB bf16 [8192][1024]
  u16*   xb   = (u16*)(ws + (40ull << 20));          // 4 MB  bf16 [8192][256]
  u16*   ipwT = (u16*)(ws + (44ull << 20));          // 384 KB bf16 [768][256]
  u16*   outwT= (u16*)(ws + (44ull << 20) + (512ull << 10));   // 128 KB [256][256]
  u16*   w1T  = (u16*)(ws + (45ull << 20));          // 512 KB bf16 [1024][256]
  u16*   w2T  = (u16*)(ws + (45ull << 20) + (512ull << 10));   // 512 KB [256][1024]

  prep_k<<<2816, 256, 0, stream>>>(x, ln1g, ln1b, xn, xb, ipw, outw, w1, w2,
                                   ipwT, outwT, w1T, w2T);
  gemm5_k<128, 128, 256, 768, 0, 6><<<384, 512, 0, stream>>>(xn, ipwT, ipb, nullptr, qkvb);
  attn_k<<<512, 512, 0, stream>>>(qkvb, o);
  gemmln_k<<<256, 512, 0, stream>>>(o, outwT, outb, xb, ln2g, ln2b, yn);
  gemm5_k<128, 128, 256, 1024, 2, 8><<<512, 512, 0, stream>>>(yn, w1T, b1, nullptr, hh);
  gemm5_k<64, 128, 1024, 256, 1, 2><<<256, 512, 0, stream>>>(hh, w2T, b2, x, (float*)d_out);
}